// Round 14
// baseline (162.135 us; speedup 1.0000x reference)
//
#include <hip/hip_runtime.h>
#include <hip/hip_fp16.h>
#include <math.h>

#define N_MESH   5151
#define NB       8
#define TT       2048
#define HID      256
#define NLAYERS  3
#define NCHUNK   16
#define CHUNK    128           // TT / NCHUNK
#define NG       101           // threshold grid values 0..100
#define TROW     136           // tab row stride (ushort)
#define NPAD     6144
#define NBLK     6             // scan n-blocks (1024 pts each, 4/thread)
#define SCAN_GRID (NBLK * NB * NCHUNK)   // 768
#define PREP_NBLK 96
#define COPY_NBLK 121          // (41208+82416)/1024 rounded up
#define MLP_NBLK  81           // 81*64 = 5184 >= 5151 (512-thr blocks)
#define PH2_NBLK  96           // 12 x 8 (512-thr blocks)
#define DENSB_NBLK 41          // 41208/1024 rounded up

// scan smem layout (bytes): hs2 @0 (528), sgv @528 (512), tab @1040 (27472)
#define OFF_SGV   528
#define OFF_TAB   1040
#define OFF_RED   28512        // k3: 4 waves x 64 floats
#define SMEM1     28512
#define SMEM3     29536

// ws layout (floats)
#define WS_DENSITY 0           // 5151
#define WS_SUM     5184        // 1
#define WS_CNT     5248        // 129 ints (cnt[0]=k2 sum, cnt[1+tix]=k3 finalize)
#define WS_PART    6144        // NB*NBLK*4*TT = 393216 -> ends 399360
                               // [WT aliases first 98304 floats: dead before k3]
#define WS_PQ      399360      // NCHUNK*NB*NPAD*2 = 1572864 -> ends 1972224

// out layout (floats)
#define OUT_BNORM  0           // 16384
#define OUT_DENSB  16384       // 41208
#define OUT_M      57592       // 16384
#define OUT_S0     73976       // 41208
#define OUT_MESHB  115184      // 82416

typedef _Float16 half8  __attribute__((ext_vector_type(8)));
typedef unsigned short u16x8 __attribute__((ext_vector_type(8)));
typedef float    f32x4  __attribute__((ext_vector_type(4)));

__device__ __forceinline__ float sigmoid_fast(float x) {
    float e = __expf(-x);
    return __builtin_amdgcn_rcpf(1.0f + e);
}

// hA byte offset with XOR swizzle (row stride 512 B fp16) -- MLP only
__device__ __forceinline__ int swz(int row, int kbyte) {
    return row * 512 + (kbyte ^ ((row & 7) << 4));
}

// 16-lane sum via DPP (VALU pipe, zero DS ops)
__device__ __forceinline__ float dpp16_sum(float v) {
    int a;
    a = __builtin_amdgcn_update_dpp(0, __float_as_int(v), 0xB1, 0xF, 0xF, true);
    v += __int_as_float(a);
    a = __builtin_amdgcn_update_dpp(0, __float_as_int(v), 0x4E, 0xF, 0xF, true);
    v += __int_as_float(a);
    a = __builtin_amdgcn_update_dpp(0, __float_as_int(v), 0x141, 0xF, 0xF, true);
    v += __int_as_float(a);
    a = __builtin_amdgcn_update_dpp(0, __float_as_int(v), 0x140, 0xF, 0xF, true);
    v += __int_as_float(a);
    return v;
}

// Direction-resolved A-table, [g][t] layout (fp16), conflict-free build.
__device__ __forceinline__ void build_table(int tid, const float* hs2,
                                            float* sgv, unsigned short* tab)
{
    if (tid < CHUNK) sgv[tid] = (hs2[tid + 1] >= hs2[tid]) ? 1.0f : -1.0f;
    for (int idx = tid; idx < NG * CHUNK; idx += 256) {
        int g = idx >> 7;
        int t = idx & 127;
        float ht = hs2[t + 1];
        bool inc = (ht >= hs2[t]);
        float bx = ht * 1000.0f;
        float y = inc ? fmaf(-10.f, (float)g, bx) : fmaf(10.f, (float)g, -bx);
        float A = __builtin_amdgcn_rcpf(1.0f + __expf(y));
        tab[g * TROW + t] = __half_as_ushort(__float2half(A));
    }
}

// ---------------------------------------------------------------------------
// k1: blocks [0,768) scan phase1; [768,864) W-fragment prep;
//     [864,985) s0/mesh_b copies + counter zeroing (block 864).
// ---------------------------------------------------------------------------
__global__ __launch_bounds__(256) void k1_scan1_prep(
    const float* __restrict__ dec, const float* __restrict__ y0,
    const float* __restrict__ mesh, const float* __restrict__ Wblk,
    float2* __restrict__ PQ, half8* __restrict__ WT,
    const float* __restrict__ s0, float* __restrict__ out,
    int* __restrict__ cnt)
{
    __shared__ __align__(16) char smem[SMEM1];
    const int tid = threadIdx.x;
    const int bid = blockIdx.x;

    if (bid >= SCAN_GRID + PREP_NBLK) {
        // ---- copies + counter init ----
        int idx = bid - (SCAN_GRID + PREP_NBLK);
        if (idx == 0 && tid < 132) cnt[tid] = 0;   // 129 counters
        const int n1 = NB * N_MESH;                 // 41208
        const int total = n1 + 2 * n1;              // 123624
#pragma unroll
        for (int k = 0; k < 4; ++k) {
            int j = idx * 1024 + k * 256 + tid;
            if (j < total) {
                if (j < n1) out[OUT_S0 + j] = s0[j];
                else {
                    int jj = j - n1;
                    out[OUT_MESHB + jj] = mesh[jj % (2 * N_MESH)];
                }
            }
        }
        return;
    }

    if (bid >= SCAN_GRID) {
        // ---- prep: gather W into per-lane MFMA fragment order ----
        int g = (bid - SCAN_GRID) * 256 + tid;   // [0, 24576)
        int l  = g & 63;
        int nt = (g >> 6) & 15;
        int kg = (g >> 10) & 7;
        int L  = g >> 13;
        int n  = nt * 16 + (l & 15);
        int kb = kg * 32 + ((l >> 4) & 3) * 8;
        const float* Wb = Wblk + (size_t)L * HID * HID;
        half8 v;
#pragma unroll
        for (int i = 0; i < 8; ++i)
            v[i] = (_Float16)Wb[(size_t)(kb + i) * HID + n];
        WT[g] = v;
        return;
    }

    float* hs2 = (float*)smem;
    float* sgv = (float*)(smem + OFF_SGV);
    unsigned short* tab = (unsigned short*)(smem + OFF_TAB);

    const int sb = bid;
    const int nb = sb % NBLK;
    const int rem = sb / NBLK;
    const int b = rem & 7;
    const int c = rem >> 3;
    const int t0 = c * CHUNK;

    if (tid < CHUNK) hs2[tid + 1] = dec[b * TT + t0 + tid];
    if (tid == 0) hs2[0] = (c == 0) ? y0[b] : dec[b * TT + t0 - 1];

    int ga[4], gb[4];
#pragma unroll
    for (int q = 0; q < 4; ++q) {
        int n = nb * 1024 + q * 256 + tid;
        if (n < N_MESH) {
            gb[q] = (int)(mesh[2 * n]     * 100.0f + 0.5f);
            ga[q] = (int)(mesh[2 * n + 1] * 100.0f + 0.5f);
        } else { ga[q] = 0; gb[q] = 0; }
    }
    __syncthreads();
    build_table(tid, hs2, sgv, tab);
    __syncthreads();

    float P[4] = {1.f, 1.f, 1.f, 1.f};
    float R[4];
    float gprev = sgv[0];
#pragma unroll
    for (int q = 0; q < 4; ++q) R[q] = -gprev;

    for (int tb = 0; tb < CHUNK; tb += 8) {
        u16x8 ra[4], rb[4];
#pragma unroll
        for (int q = 0; q < 4; ++q) {
            ra[q] = *(const u16x8*)&tab[ga[q] * TROW + tb];
            rb[q] = *(const u16x8*)&tab[gb[q] * TROW + tb];
        }
        float4 sA = *(const float4*)&sgv[tb];
        float4 sB = *(const float4*)&sgv[tb + 4];
        float sg8[8] = {sA.x, sA.y, sA.z, sA.w, sB.x, sB.y, sB.z, sB.w};
#pragma unroll
        for (int j = 0; j < 8; ++j) {
            float sgt = sg8[j];
            float dl = gprev - sgt;      // 0 or +-2, wave-uniform
            gprev = sgt;
            bool inc = sgt > 0.0f;
#pragma unroll
            for (int q = 0; q < 4; ++q) {
                unsigned short u = inc ? ra[q][j] : rb[q][j];
                float A = __half2float(__ushort_as_half(u));
                float r = R[q] + dl;
                P[q] *= A;
                R[q] = r * A;
            }
        }
    }
    size_t basew = ((size_t)(c * NB + b)) * NPAD;
#pragma unroll
    for (int q = 0; q < 4; ++q) {
        int n = nb * 1024 + q * 256 + tid;
        float2 v; v.x = P[q]; v.y = R[q] + gprev;
        PQ[basew + n] = v;
    }
}

// ---------------------------------------------------------------------------
// k2: blocks [0,81) = MFMA density MLP + last-arriver density-sum;
//     blocks [81,177) = phase2 (512 thr).
// ---------------------------------------------------------------------------
__global__ __launch_bounds__(512) void k2_mlp_phase2(
    const float* __restrict__ mesh, const float* __restrict__ Win,
    const float* __restrict__ bin,  const half8* __restrict__ WT,
    const float* __restrict__ bblk, const float* __restrict__ Wout,
    const float* __restrict__ bout, float* __restrict__ density,
    const float* __restrict__ s0_in, float* __restrict__ PQf,
    int* __restrict__ cnt, float* __restrict__ sum_ptr)
{
    __shared__ __align__(16) char hA[64 * 512];   // 32 KB
    __shared__ float psum[4][16][2];
    __shared__ int sold;
    __shared__ float red8[8];
    const int tid  = threadIdx.x;

    if (blockIdx.x >= MLP_NBLK) {
        int idx = blockIdx.x - MLP_NBLK;   // 0..95
        int nbb = idx % 12;
        int b   = idx / 12;
        int n   = nbb * 512 + tid;
        const float2* PQ = (const float2*)PQf;
        float2 v[NCHUNK];
#pragma unroll
        for (int c = 0; c < NCHUNK; ++c)
            v[c] = PQ[((size_t)(c * NB + b)) * NPAD + n];
        float s = (n < N_MESH) ? s0_in[b * N_MESH + n] : 0.f;
#pragma unroll
        for (int c = 0; c < NCHUNK; ++c) {
            size_t ix = ((size_t)(c * NB + b)) * NPAD + n;
            PQf[2 * ix] = s;
            s = fmaf(v[c].x, s, v[c].y);
        }
        return;
    }

    const int w    = tid >> 6;
    const int lane = tid & 63;
    const int rl   = lane & 15;
    const int cg   = lane >> 4;
    const int mt   = w & 3;
    const int nh   = w >> 2;
    const int row0 = blockIdx.x * 64;

    float hreg[8][4];

    {
        float m0[4], m1[4];
#pragma unroll
        for (int r = 0; r < 4; ++r) {
            int gr = row0 + mt * 16 + cg * 4 + r;
            if (gr < N_MESH) { m0[r] = mesh[2 * gr]; m1[r] = mesh[2 * gr + 1]; }
            else { m0[r] = 0.f; m1[r] = 0.f; }
        }
#pragma unroll
        for (int j = 0; j < 8; ++j) {
            int col = nh * 128 + j * 16 + rl;
            float wa = Win[col], wb = Win[HID + col], bi = bin[col];
#pragma unroll
            for (int r = 0; r < 4; ++r) {
                float v = fmaxf(fmaf(m0[r], wa, fmaf(m1[r], wb, bi)), 0.f);
                hreg[j][r] = v;
                *(_Float16*)(hA + swz(mt * 16 + cg * 4 + r, col * 2)) =
                    (_Float16)v;
            }
        }
    }
    __syncthreads();

    for (int L = 0; L < NLAYERS; ++L) {
        half8 af[8];
#pragma unroll
        for (int kg = 0; kg < 8; ++kg)
            af[kg] = *(const half8*)(hA + swz(mt * 16 + rl, kg * 64 + cg * 16));
        __syncthreads();

        float bias[8];
#pragma unroll
        for (int j = 0; j < 8; ++j)
            bias[j] = bblk[L * HID + nh * 128 + j * 16 + rl];

        f32x4 acc[8];
#pragma unroll
        for (int j = 0; j < 8; ++j) acc[j] = (f32x4){0.f, 0.f, 0.f, 0.f};

        const half8* WTL = WT + ((size_t)(L * 8) * 16 + nh * 8) * 64 + lane;
        half8 b0[8], b1[8];
#pragma unroll
        for (int j = 0; j < 8; ++j) b0[j] = WTL[(size_t)j * 64];
#pragma unroll
        for (int kg2 = 0; kg2 < 8; kg2 += 2) {
#pragma unroll
            for (int j = 0; j < 8; ++j)
                b1[j] = WTL[(size_t)(kg2 + 1) * 1024 + (size_t)j * 64];
#pragma unroll
            for (int j = 0; j < 8; ++j)
                acc[j] = __builtin_amdgcn_mfma_f32_16x16x32_f16(
                    af[kg2], b0[j], acc[j], 0, 0, 0);
            if (kg2 + 2 < 8) {
#pragma unroll
                for (int j = 0; j < 8; ++j)
                    b0[j] = WTL[(size_t)(kg2 + 2) * 1024 + (size_t)j * 64];
            }
#pragma unroll
            for (int j = 0; j < 8; ++j)
                acc[j] = __builtin_amdgcn_mfma_f32_16x16x32_f16(
                    af[kg2 + 1], b1[j], acc[j], 0, 0, 0);
        }

#pragma unroll
        for (int j = 0; j < 8; ++j) {
            int col = nh * 128 + j * 16 + rl;
#pragma unroll
            for (int r = 0; r < 4; ++r) {
                float v = hreg[j][r] + fmaxf(acc[j][r] + bias[j], 0.f);
                hreg[j][r] = v;
                if (L < NLAYERS - 1)
                    *(_Float16*)(hA + swz(mt * 16 + cg * 4 + r, col * 2)) =
                        (_Float16)v;
            }
        }
        if (L < NLAYERS - 1) __syncthreads();
    }

    {
        float p[4] = {0.f, 0.f, 0.f, 0.f};
#pragma unroll
        for (int j = 0; j < 8; ++j) {
            float wo = Wout[nh * 128 + j * 16 + rl];
#pragma unroll
            for (int r = 0; r < 4; ++r) p[r] = fmaf(hreg[j][r], wo, p[r]);
        }
#pragma unroll
        for (int st = 1; st < 16; st <<= 1)
#pragma unroll
            for (int r = 0; r < 4; ++r) p[r] += __shfl_xor(p[r], st, 64);
        if (rl == 0) {
#pragma unroll
            for (int r = 0; r < 4; ++r) psum[mt][cg * 4 + r][nh] = p[r];
        }
    }
    __syncthreads();
    if (tid < 64) {
        int gr = row0 + tid;
        float pp = psum[tid >> 4][tid & 15][0] + psum[tid >> 4][tid & 15][1];
        if (gr < N_MESH) density[gr] = sigmoid_fast(pp + bout[0]);
    }

    // ---- last-arriver density sum ----
    __threadfence();
    if (tid == 0) sold = atomicAdd(&cnt[0], 1);
    __syncthreads();
    if (sold == MLP_NBLK - 1) {
        __threadfence();
        float p = 0.f;
        for (int i = tid; i < N_MESH; i += 512) p += density[i];
#pragma unroll
        for (int st = 1; st < 64; st <<= 1) p += __shfl_xor(p, st, 64);
        if (lane == 0) red8[w] = p;
        __syncthreads();
        if (tid == 0) {
            float s = 0.f;
#pragma unroll
            for (int i = 0; i < 8; ++i) s += red8[i];
            sum_ptr[0] = s;
        }
    }
}

// ---------------------------------------------------------------------------
// k3: blocks [0,768) = phase3 replay + last-arriver m/b_norm finalize;
//     blocks [768,809) = density_b copy.
// ---------------------------------------------------------------------------
__global__ __launch_bounds__(256) void k3_phase3_fin(
    const float* __restrict__ dec, const float* __restrict__ y0,
    const float* __restrict__ mesh, const float* __restrict__ density,
    const float* __restrict__ PQf, float* __restrict__ partials,
    const float* __restrict__ sum_ptr, float* __restrict__ out,
    int* __restrict__ cnt)
{
    __shared__ __align__(16) char smem[SMEM3];
    __shared__ int soldv;
    const int tid = threadIdx.x;
    const int bx = blockIdx.x;

    if (bx >= SCAN_GRID) {
        // ---- density_b copy ----
        int idx = bx - SCAN_GRID;
#pragma unroll
        for (int k = 0; k < 4; ++k) {
            int j = idx * 1024 + k * 256 + tid;
            if (j < NB * N_MESH) out[OUT_DENSB + j] = density[j % N_MESH];
        }
        return;
    }

    float* hs2 = (float*)smem;
    float* sgv = (float*)(smem + OFF_SGV);
    unsigned short* tab = (unsigned short*)(smem + OFF_TAB);
    float* red = (float*)(smem + OFF_RED);   // [4 waves][64]

    const int nb = bx % NBLK;
    const int rem = bx / NBLK;
    const int b = rem & 7;
    const int c = rem >> 3;
    const int t0 = c * CHUNK;
    const int lane = tid & 63, w = tid >> 6;

    if (tid < CHUNK) hs2[tid + 1] = dec[b * TT + t0 + tid];
    if (tid == 0) hs2[0] = (c == 0) ? y0[b] : dec[b * TT + t0 - 1];
    __syncthreads();
    build_table(tid, hs2, sgv, tab);
    __syncthreads();

    int ga[4], gb[4];
    float d[4], z[4];
    float gprev = sgv[0];
#pragma unroll
    for (int q = 0; q < 4; ++q) {
        int n = nb * 1024 + q * 256 + tid;
        float S = 0.f;
        if (n < N_MESH) {
            gb[q] = (int)(mesh[2 * n]     * 100.0f + 0.5f);
            ga[q] = (int)(mesh[2 * n + 1] * 100.0f + 0.5f);
            d[q]  = density[n];
            S = PQf[2 * (((size_t)(c * NB + b)) * NPAD + n)];
        } else { ga[q] = 0; gb[q] = 0; d[q] = 0.f; }
        z[q] = S - gprev;
    }

    float* pout = partials + ((size_t)((b * NBLK + nb) * 4 + w)) * TT + t0;

    for (int tb = 0; tb < CHUNK; tb += 16) {
        float v[16];
#pragma unroll
        for (int hh = 0; hh < 2; ++hh) {
            int tw = tb + hh * 8;
            u16x8 ra[4], rb[4];
#pragma unroll
            for (int q = 0; q < 4; ++q) {
                ra[q] = *(const u16x8*)&tab[ga[q] * TROW + tw];
                rb[q] = *(const u16x8*)&tab[gb[q] * TROW + tw];
            }
            float4 sA = *(const float4*)&sgv[tw];
            float4 sB = *(const float4*)&sgv[tw + 4];
            float sg8[8] = {sA.x, sA.y, sA.z, sA.w, sB.x, sB.y, sB.z, sB.w};
#pragma unroll
            for (int j = 0; j < 8; ++j) {
                float sgt = sg8[j];
                float dl = gprev - sgt;
                gprev = sgt;
                bool inc = sgt > 0.0f;
#pragma unroll
                for (int q = 0; q < 4; ++q) {
                    unsigned short u = inc ? ra[q][j] : rb[q][j];
                    float A = __half2float(__ushort_as_half(u));
                    z[q] = (z[q] + dl) * A;
                }
                float a0 = d[0] * z[0];
                float a1 = d[1] * z[1];
                a0 = fmaf(d[2], z[2], a0);
                a1 = fmaf(d[3], z[3], a1);
                v[hh * 8 + j] = a0 + a1;
            }
        }
#pragma unroll
        for (int j = 0; j < 16; ++j) v[j] = dpp16_sum(v[j]);
        float outv = v[0];
#pragma unroll
        for (int j = 1; j < 16; ++j) if ((lane & 15) == j) outv = v[j];
        red[w * 64 + (lane & 15) * 4 + (lane >> 4)] = outv;
        if (lane < 16) {
            float4 s4 = *(const float4*)&red[w * 64 + lane * 4];
            pout[tb + lane] = (s4.x + s4.y) + (s4.z + s4.w);
        }
    }

    // ---- last-arriver finalize for this (b,c): m and b_norm over 128 t ----
    __threadfence();
    if (tid == 0) soldv = atomicAdd(&cnt[1 + ((c << 3) | b)], 1);
    __syncthreads();
    if (soldv == NBLK - 1) {
        __threadfence();
        if (tid < CHUNK) {
            int t = t0 + tid;
            float acc = 0.f;
#pragma unroll
            for (int r = 0; r < 24; ++r)
                acc += partials[(size_t)(b * 24 + r) * TT + t];
            float h  = dec[b * TT + t];
            float hp = t ? dec[b * TT + t - 1] : y0[b];
            float g  = (h >= hp) ? 1.0f : -1.0f;
            float D = sum_ptr[0];
            float m = (acc + g * D) / D;
            out[OUT_M + b * TT + t] = m;
            out[OUT_BNORM + b * TT + t] = 0.5f * m + 0.5f;
        }
    }
}

extern "C" void kernel_launch(void* const* d_in, const int* in_sizes, int n_in,
                              void* d_out, int out_size, void* d_ws, size_t ws_size,
                              hipStream_t stream) {
    const float* dec  = (const float*)d_in[1];
    const float* s0   = (const float*)d_in[2];
    const float* y0   = (const float*)d_in[3];
    const float* mesh = (const float*)d_in[4];
    const float* Win  = (const float*)d_in[5];
    const float* bin  = (const float*)d_in[6];
    const float* Wblk = (const float*)d_in[7];
    const float* bblk = (const float*)d_in[8];
    const float* Wout = (const float*)d_in[9];
    const float* bout = (const float*)d_in[10];
    float* out = (float*)d_out;
    float* ws  = (float*)d_ws;

    float*  density  = ws + WS_DENSITY;
    float*  sum_ptr  = ws + WS_SUM;
    int*    cnt      = (int*)(ws + WS_CNT);
    float*  partials = ws + WS_PART;
    float*  pqf      = ws + WS_PQ;
    float2* pq       = (float2*)pqf;
    half8*  wt       = (half8*)(ws + WS_PART);   // aliases partials (dead by k3)

    k1_scan1_prep<<<SCAN_GRID + PREP_NBLK + COPY_NBLK, 256, 0, stream>>>(
        dec, y0, mesh, Wblk, pq, wt, s0, out, cnt);
    k2_mlp_phase2<<<MLP_NBLK + PH2_NBLK, 512, 0, stream>>>(
        mesh, Win, bin, wt, bblk, Wout, bout, density, s0, pqf, cnt, sum_ptr);
    k3_phase3_fin<<<SCAN_GRID + DENSB_NBLK, 256, 0, stream>>>(
        dec, y0, mesh, density, pqf, partials, sum_ptr, out, cnt);
}

// Round 15
// 82.256 us; speedup vs baseline: 1.9711x; 1.9711x over previous
//
#include <hip/hip_runtime.h>
#include <hip/hip_fp16.h>
#include <math.h>

#define N_MESH   5151
#define NB       8
#define TT       2048
#define HID      256
#define NLAYERS  3
#define NCHUNK   16
#define CHUNK    128           // TT / NCHUNK
#define NG       101           // threshold grid values 0..100
#define TROW     136           // tab row stride (ushort)
#define NPAD     6144
#define NBLK     6             // scan n-blocks (1024 pts each, 4/thread)
#define SCAN_GRID (NBLK * NB * NCHUNK)   // 768
#define PREP_NBLK 96
#define COPY_NBLK 121          // (41208+82416)/1024 rounded up
#define MLP_NBLK  81           // 81*64 = 5184 >= 5151 (512-thr blocks)
#define PH2_NBLK  96           // 12 x 8 (512-thr blocks)
#define DENSB_NBLK 41          // 41208/1024 rounded up

// scan smem layout (bytes): hs2 @0 (528), sgv @528 (512), tab @1040 (27472)
#define OFF_SGV   528
#define OFF_TAB   1040
#define OFF_RED   28512        // k3: 4 waves x 64 floats
#define SMEM1     28512
#define SMEM3     29536

// ws layout (floats)
#define WS_DENSITY 0           // 5151
#define WS_SUM     5184        // 1
#define WS_PART    6144        // NB*NBLK*4*TT = 393216 -> ends 399360
                               // [WT aliases first 98304 floats: dead before k3]
#define WS_PQ      399360      // NCHUNK*NB*NPAD*2 = 1572864 -> ends 1972224

// out layout (floats)
#define OUT_BNORM  0           // 16384
#define OUT_DENSB  16384       // 41208
#define OUT_M      57592       // 16384
#define OUT_S0     73976       // 41208
#define OUT_MESHB  115184      // 82416

typedef _Float16 half8  __attribute__((ext_vector_type(8)));
typedef unsigned short u16x8 __attribute__((ext_vector_type(8)));
typedef float    f32x4  __attribute__((ext_vector_type(4)));

__device__ __forceinline__ float sigmoid_fast(float x) {
    float e = __expf(-x);
    return __builtin_amdgcn_rcpf(1.0f + e);
}

// hA byte offset with XOR swizzle (row stride 512 B fp16) -- MLP only
__device__ __forceinline__ int swz(int row, int kbyte) {
    return row * 512 + (kbyte ^ ((row & 7) << 4));
}

// 16-lane sum via DPP (VALU pipe, zero DS ops)
__device__ __forceinline__ float dpp16_sum(float v) {
    int a;
    a = __builtin_amdgcn_update_dpp(0, __float_as_int(v), 0xB1, 0xF, 0xF, true);
    v += __int_as_float(a);
    a = __builtin_amdgcn_update_dpp(0, __float_as_int(v), 0x4E, 0xF, 0xF, true);
    v += __int_as_float(a);
    a = __builtin_amdgcn_update_dpp(0, __float_as_int(v), 0x141, 0xF, 0xF, true);
    v += __int_as_float(a);
    a = __builtin_amdgcn_update_dpp(0, __float_as_int(v), 0x140, 0xF, 0xF, true);
    v += __int_as_float(a);
    return v;
}

// Direction-resolved A-table, [g][t] layout (fp16), conflict-free build.
__device__ __forceinline__ void build_table(int tid, const float* hs2,
                                            float* sgv, unsigned short* tab)
{
    if (tid < CHUNK) sgv[tid] = (hs2[tid + 1] >= hs2[tid]) ? 1.0f : -1.0f;
    for (int idx = tid; idx < NG * CHUNK; idx += 256) {
        int g = idx >> 7;
        int t = idx & 127;
        float ht = hs2[t + 1];
        bool inc = (ht >= hs2[t]);
        float bx = ht * 1000.0f;
        float y = inc ? fmaf(-10.f, (float)g, bx) : fmaf(10.f, (float)g, -bx);
        float A = __builtin_amdgcn_rcpf(1.0f + __expf(y));
        tab[g * TROW + t] = __half_as_ushort(__float2half(A));
    }
}

// ---------------------------------------------------------------------------
// k1: blocks [0,768) scan phase1; [768,864) W-fragment prep;
//     [864,985) s0/mesh_b output copies (dependency-free).
// ---------------------------------------------------------------------------
__global__ __launch_bounds__(256) void k1_scan1_prep(
    const float* __restrict__ dec, const float* __restrict__ y0,
    const float* __restrict__ mesh, const float* __restrict__ Wblk,
    float2* __restrict__ PQ, half8* __restrict__ WT,
    const float* __restrict__ s0, float* __restrict__ out)
{
    __shared__ __align__(16) char smem[SMEM1];
    const int tid = threadIdx.x;
    const int bid = blockIdx.x;

    if (bid >= SCAN_GRID + PREP_NBLK) {
        // ---- s0 / mesh_b copies ----
        int idx = bid - (SCAN_GRID + PREP_NBLK);
        const int n1 = NB * N_MESH;                 // 41208
        const int total = n1 + 2 * n1;              // 123624
#pragma unroll
        for (int k = 0; k < 4; ++k) {
            int j = idx * 1024 + k * 256 + tid;
            if (j < total) {
                if (j < n1) out[OUT_S0 + j] = s0[j];
                else {
                    int jj = j - n1;
                    out[OUT_MESHB + jj] = mesh[jj % (2 * N_MESH)];
                }
            }
        }
        return;
    }

    if (bid >= SCAN_GRID) {
        // ---- prep: gather W into per-lane MFMA fragment order ----
        int g = (bid - SCAN_GRID) * 256 + tid;   // [0, 24576)
        int l  = g & 63;
        int nt = (g >> 6) & 15;
        int kg = (g >> 10) & 7;
        int L  = g >> 13;
        int n  = nt * 16 + (l & 15);
        int kb = kg * 32 + ((l >> 4) & 3) * 8;
        const float* Wb = Wblk + (size_t)L * HID * HID;
        half8 v;
#pragma unroll
        for (int i = 0; i < 8; ++i)
            v[i] = (_Float16)Wb[(size_t)(kb + i) * HID + n];
        WT[g] = v;
        return;
    }

    float* hs2 = (float*)smem;
    float* sgv = (float*)(smem + OFF_SGV);
    unsigned short* tab = (unsigned short*)(smem + OFF_TAB);

    const int sb = bid;
    const int nb = sb % NBLK;
    const int rem = sb / NBLK;
    const int b = rem & 7;
    const int c = rem >> 3;
    const int t0 = c * CHUNK;

    if (tid < CHUNK) hs2[tid + 1] = dec[b * TT + t0 + tid];
    if (tid == 0) hs2[0] = (c == 0) ? y0[b] : dec[b * TT + t0 - 1];

    int ga[4], gb[4];
#pragma unroll
    for (int q = 0; q < 4; ++q) {
        int n = nb * 1024 + q * 256 + tid;
        if (n < N_MESH) {
            gb[q] = (int)(mesh[2 * n]     * 100.0f + 0.5f);
            ga[q] = (int)(mesh[2 * n + 1] * 100.0f + 0.5f);
        } else { ga[q] = 0; gb[q] = 0; }
    }
    __syncthreads();
    build_table(tid, hs2, sgv, tab);
    __syncthreads();

    float P[4] = {1.f, 1.f, 1.f, 1.f};
    float R[4];
    float gprev = sgv[0];
#pragma unroll
    for (int q = 0; q < 4; ++q) R[q] = -gprev;

    for (int tb = 0; tb < CHUNK; tb += 8) {
        u16x8 ra[4], rb[4];
#pragma unroll
        for (int q = 0; q < 4; ++q) {
            ra[q] = *(const u16x8*)&tab[ga[q] * TROW + tb];
            rb[q] = *(const u16x8*)&tab[gb[q] * TROW + tb];
        }
        float4 sA = *(const float4*)&sgv[tb];
        float4 sB = *(const float4*)&sgv[tb + 4];
        float sg8[8] = {sA.x, sA.y, sA.z, sA.w, sB.x, sB.y, sB.z, sB.w};
#pragma unroll
        for (int j = 0; j < 8; ++j) {
            float sgt = sg8[j];
            float dl = gprev - sgt;      // 0 or +-2, wave-uniform
            gprev = sgt;
            bool inc = sgt > 0.0f;
#pragma unroll
            for (int q = 0; q < 4; ++q) {
                unsigned short u = inc ? ra[q][j] : rb[q][j];
                float A = __half2float(__ushort_as_half(u));
                float r = R[q] + dl;
                P[q] *= A;
                R[q] = r * A;
            }
        }
    }
    size_t basew = ((size_t)(c * NB + b)) * NPAD;
#pragma unroll
    for (int q = 0; q < 4; ++q) {
        int n = nb * 1024 + q * 256 + tid;
        float2 v; v.x = P[q]; v.y = R[q] + gprev;
        PQ[basew + n] = v;
    }
}

// ---------------------------------------------------------------------------
// k2: blocks [0,81) = MFMA density MLP (proven body, 512 thr);
//     blocks [81,177) = phase2 (512 thr).
// ---------------------------------------------------------------------------
__global__ __launch_bounds__(512) void k2_mlp_phase2(
    const float* __restrict__ mesh, const float* __restrict__ Win,
    const float* __restrict__ bin,  const half8* __restrict__ WT,
    const float* __restrict__ bblk, const float* __restrict__ Wout,
    const float* __restrict__ bout, float* __restrict__ density,
    const float* __restrict__ s0_in, float* __restrict__ PQf)
{
    __shared__ __align__(16) char hA[64 * 512];   // 32 KB
    __shared__ float psum[4][16][2];
    const int tid  = threadIdx.x;

    if (blockIdx.x >= MLP_NBLK) {
        int idx = blockIdx.x - MLP_NBLK;   // 0..95
        int nbb = idx % 12;
        int b   = idx / 12;
        int n   = nbb * 512 + tid;
        const float2* PQ = (const float2*)PQf;
        float2 v[NCHUNK];
#pragma unroll
        for (int c = 0; c < NCHUNK; ++c)
            v[c] = PQ[((size_t)(c * NB + b)) * NPAD + n];
        float s = (n < N_MESH) ? s0_in[b * N_MESH + n] : 0.f;
#pragma unroll
        for (int c = 0; c < NCHUNK; ++c) {
            size_t ix = ((size_t)(c * NB + b)) * NPAD + n;
            PQf[2 * ix] = s;
            s = fmaf(v[c].x, s, v[c].y);
        }
        return;
    }

    const int w    = tid >> 6;
    const int lane = tid & 63;
    const int rl   = lane & 15;
    const int cg   = lane >> 4;
    const int mt   = w & 3;
    const int nh   = w >> 2;
    const int row0 = blockIdx.x * 64;

    float hreg[8][4];

    {
        float m0[4], m1[4];
#pragma unroll
        for (int r = 0; r < 4; ++r) {
            int gr = row0 + mt * 16 + cg * 4 + r;
            if (gr < N_MESH) { m0[r] = mesh[2 * gr]; m1[r] = mesh[2 * gr + 1]; }
            else { m0[r] = 0.f; m1[r] = 0.f; }
        }
#pragma unroll
        for (int j = 0; j < 8; ++j) {
            int col = nh * 128 + j * 16 + rl;
            float wa = Win[col], wb = Win[HID + col], bi = bin[col];
#pragma unroll
            for (int r = 0; r < 4; ++r) {
                float v = fmaxf(fmaf(m0[r], wa, fmaf(m1[r], wb, bi)), 0.f);
                hreg[j][r] = v;
                *(_Float16*)(hA + swz(mt * 16 + cg * 4 + r, col * 2)) =
                    (_Float16)v;
            }
        }
    }
    __syncthreads();

    for (int L = 0; L < NLAYERS; ++L) {
        half8 af[8];
#pragma unroll
        for (int kg = 0; kg < 8; ++kg)
            af[kg] = *(const half8*)(hA + swz(mt * 16 + rl, kg * 64 + cg * 16));
        __syncthreads();

        float bias[8];
#pragma unroll
        for (int j = 0; j < 8; ++j)
            bias[j] = bblk[L * HID + nh * 128 + j * 16 + rl];

        f32x4 acc[8];
#pragma unroll
        for (int j = 0; j < 8; ++j) acc[j] = (f32x4){0.f, 0.f, 0.f, 0.f};

        const half8* WTL = WT + ((size_t)(L * 8) * 16 + nh * 8) * 64 + lane;
        half8 b0[8], b1[8];
#pragma unroll
        for (int j = 0; j < 8; ++j) b0[j] = WTL[(size_t)j * 64];
#pragma unroll
        for (int kg2 = 0; kg2 < 8; kg2 += 2) {
#pragma unroll
            for (int j = 0; j < 8; ++j)
                b1[j] = WTL[(size_t)(kg2 + 1) * 1024 + (size_t)j * 64];
#pragma unroll
            for (int j = 0; j < 8; ++j)
                acc[j] = __builtin_amdgcn_mfma_f32_16x16x32_f16(
                    af[kg2], b0[j], acc[j], 0, 0, 0);
            if (kg2 + 2 < 8) {
#pragma unroll
                for (int j = 0; j < 8; ++j)
                    b0[j] = WTL[(size_t)(kg2 + 2) * 1024 + (size_t)j * 64];
            }
#pragma unroll
            for (int j = 0; j < 8; ++j)
                acc[j] = __builtin_amdgcn_mfma_f32_16x16x32_f16(
                    af[kg2 + 1], b1[j], acc[j], 0, 0, 0);
        }

#pragma unroll
        for (int j = 0; j < 8; ++j) {
            int col = nh * 128 + j * 16 + rl;
#pragma unroll
            for (int r = 0; r < 4; ++r) {
                float v = hreg[j][r] + fmaxf(acc[j][r] + bias[j], 0.f);
                hreg[j][r] = v;
                if (L < NLAYERS - 1)
                    *(_Float16*)(hA + swz(mt * 16 + cg * 4 + r, col * 2)) =
                        (_Float16)v;
            }
        }
        if (L < NLAYERS - 1) __syncthreads();
    }

    {
        float p[4] = {0.f, 0.f, 0.f, 0.f};
#pragma unroll
        for (int j = 0; j < 8; ++j) {
            float wo = Wout[nh * 128 + j * 16 + rl];
#pragma unroll
            for (int r = 0; r < 4; ++r) p[r] = fmaf(hreg[j][r], wo, p[r]);
        }
#pragma unroll
        for (int st = 1; st < 16; st <<= 1)
#pragma unroll
            for (int r = 0; r < 4; ++r) p[r] += __shfl_xor(p[r], st, 64);
        if (rl == 0) {
#pragma unroll
            for (int r = 0; r < 4; ++r) psum[mt][cg * 4 + r][nh] = p[r];
        }
    }
    __syncthreads();
    if (tid < 64) {
        int gr = row0 + tid;
        float pp = psum[tid >> 4][tid & 15][0] + psum[tid >> 4][tid & 15][1];
        if (gr < N_MESH) density[gr] = sigmoid_fast(pp + bout[0]);
    }
}

// ---------------------------------------------------------------------------
// k3: blocks [0,768) = phase3 replay; block 768 = density sum;
//     blocks [769,810) = density_b copy (density ready since k2).
// ---------------------------------------------------------------------------
__global__ __launch_bounds__(256) void k3_phase3_sum(
    const float* __restrict__ dec, const float* __restrict__ y0,
    const float* __restrict__ mesh, const float* __restrict__ density,
    const float* __restrict__ PQf, float* __restrict__ partials,
    float* __restrict__ sum_out, float* __restrict__ out)
{
    __shared__ __align__(16) char smem[SMEM3];
    const int tid = threadIdx.x;
    const int bx = blockIdx.x;

    if (bx >= SCAN_GRID + 1) {
        // ---- density_b copy ----
        int idx = bx - (SCAN_GRID + 1);
#pragma unroll
        for (int k = 0; k < 4; ++k) {
            int j = idx * 1024 + k * 256 + tid;
            if (j < NB * N_MESH) out[OUT_DENSB + j] = density[j % N_MESH];
        }
        return;
    }
    if (bx == SCAN_GRID) {
        // ---- density sum ----
        float* red4 = (float*)smem;
        float p = 0.f;
        for (int i = tid; i < N_MESH; i += 256) p += density[i];
#pragma unroll
        for (int st = 1; st < 64; st <<= 1) p += __shfl_xor(p, st, 64);
        int lane = tid & 63, w = tid >> 6;
        if (lane == 0) red4[w] = p;
        __syncthreads();
        if (tid == 0) sum_out[0] = red4[0] + red4[1] + red4[2] + red4[3];
        return;
    }

    float* hs2 = (float*)smem;
    float* sgv = (float*)(smem + OFF_SGV);
    unsigned short* tab = (unsigned short*)(smem + OFF_TAB);
    float* red = (float*)(smem + OFF_RED);   // [4 waves][64]

    const int nb = bx % NBLK;
    const int rem = bx / NBLK;
    const int b = rem & 7;
    const int c = rem >> 3;
    const int t0 = c * CHUNK;
    const int lane = tid & 63, w = tid >> 6;

    if (tid < CHUNK) hs2[tid + 1] = dec[b * TT + t0 + tid];
    if (tid == 0) hs2[0] = (c == 0) ? y0[b] : dec[b * TT + t0 - 1];
    __syncthreads();
    build_table(tid, hs2, sgv, tab);
    __syncthreads();

    int ga[4], gb[4];
    float d[4], z[4];
    float gprev = sgv[0];
#pragma unroll
    for (int q = 0; q < 4; ++q) {
        int n = nb * 1024 + q * 256 + tid;
        float S = 0.f;
        if (n < N_MESH) {
            gb[q] = (int)(mesh[2 * n]     * 100.0f + 0.5f);
            ga[q] = (int)(mesh[2 * n + 1] * 100.0f + 0.5f);
            d[q]  = density[n];
            S = PQf[2 * (((size_t)(c * NB + b)) * NPAD + n)];
        } else { ga[q] = 0; gb[q] = 0; d[q] = 0.f; }
        z[q] = S - gprev;
    }

    float* pout = partials + ((size_t)((b * NBLK + nb) * 4 + w)) * TT + t0;

    for (int tb = 0; tb < CHUNK; tb += 16) {
        float v[16];
#pragma unroll
        for (int hh = 0; hh < 2; ++hh) {
            int tw = tb + hh * 8;
            u16x8 ra[4], rb[4];
#pragma unroll
            for (int q = 0; q < 4; ++q) {
                ra[q] = *(const u16x8*)&tab[ga[q] * TROW + tw];
                rb[q] = *(const u16x8*)&tab[gb[q] * TROW + tw];
            }
            float4 sA = *(const float4*)&sgv[tw];
            float4 sB = *(const float4*)&sgv[tw + 4];
            float sg8[8] = {sA.x, sA.y, sA.z, sA.w, sB.x, sB.y, sB.z, sB.w};
#pragma unroll
            for (int j = 0; j < 8; ++j) {
                float sgt = sg8[j];
                float dl = gprev - sgt;
                gprev = sgt;
                bool inc = sgt > 0.0f;
#pragma unroll
                for (int q = 0; q < 4; ++q) {
                    unsigned short u = inc ? ra[q][j] : rb[q][j];
                    float A = __half2float(__ushort_as_half(u));
                    z[q] = (z[q] + dl) * A;
                }
                float a0 = d[0] * z[0];
                float a1 = d[1] * z[1];
                a0 = fmaf(d[2], z[2], a0);
                a1 = fmaf(d[3], z[3], a1);
                v[hh * 8 + j] = a0 + a1;
            }
        }
#pragma unroll
        for (int j = 0; j < 16; ++j) v[j] = dpp16_sum(v[j]);
        float outv = v[0];
#pragma unroll
        for (int j = 1; j < 16; ++j) if ((lane & 15) == j) outv = v[j];
        red[w * 64 + (lane & 15) * 4 + (lane >> 4)] = outv;
        if (lane < 16) {
            float4 s4 = *(const float4*)&red[w * 64 + lane * 4];
            pout[tb + lane] = (s4.x + s4.y) + (s4.z + s4.w);
        }
    }
}

// ---------------------------------------------------------------------------
// k4: m / b_norm finalize only (64 blocks).
// ---------------------------------------------------------------------------
__global__ __launch_bounds__(256) void k4_outputs(
    const float* __restrict__ partials, const float* __restrict__ sum_ptr,
    const float* __restrict__ dec, const float* __restrict__ y0,
    float* __restrict__ out)
{
    int i = blockIdx.x * blockDim.x + threadIdx.x;   // < 16384
    int b = i >> 11, t = i & (TT - 1);
    float h  = dec[b * TT + t];
    float hp = t ? dec[b * TT + t - 1] : y0[b];
    float g  = (h >= hp) ? 1.0f : -1.0f;
    float acc = 0.f;
#pragma unroll 8
    for (int k = 0; k < NBLK * 4; ++k)
        acc += partials[((size_t)(b * NBLK * 4 + k)) * TT + t];
    float D = sum_ptr[0];
    float m = (acc + g * D) / D;
    out[OUT_M + i] = m;
    out[OUT_BNORM + i] = 0.5f * m + 0.5f;
}

extern "C" void kernel_launch(void* const* d_in, const int* in_sizes, int n_in,
                              void* d_out, int out_size, void* d_ws, size_t ws_size,
                              hipStream_t stream) {
    const float* dec  = (const float*)d_in[1];
    const float* s0   = (const float*)d_in[2];
    const float* y0   = (const float*)d_in[3];
    const float* mesh = (const float*)d_in[4];
    const float* Win  = (const float*)d_in[5];
    const float* bin  = (const float*)d_in[6];
    const float* Wblk = (const float*)d_in[7];
    const float* bblk = (const float*)d_in[8];
    const float* Wout = (const float*)d_in[9];
    const float* bout = (const float*)d_in[10];
    float* out = (float*)d_out;
    float* ws  = (float*)d_ws;

    float*  density  = ws + WS_DENSITY;
    float*  sum_ptr  = ws + WS_SUM;
    float*  partials = ws + WS_PART;
    float*  pqf      = ws + WS_PQ;
    float2* pq       = (float2*)pqf;
    half8*  wt       = (half8*)(ws + WS_PART);   // aliases partials (dead by k3)

    k1_scan1_prep<<<SCAN_GRID + PREP_NBLK + COPY_NBLK, 256, 0, stream>>>(
        dec, y0, mesh, Wblk, pq, wt, s0, out);
    k2_mlp_phase2<<<MLP_NBLK + PH2_NBLK, 512, 0, stream>>>(
        mesh, Win, bin, wt, bblk, Wout, bout, density, s0, pqf);
    k3_phase3_sum<<<SCAN_GRID + 1 + DENSB_NBLK, 256, 0, stream>>>(
        dec, y0, mesh, density, pqf, partials, sum_ptr, out);
    k4_outputs<<<64, 256, 0, stream>>>(
        partials, sum_ptr, dec, y0, out);
}

// Round 16
// 74.389 us; speedup vs baseline: 2.1795x; 1.1057x over previous
//
#include <hip/hip_runtime.h>
#include <hip/hip_fp16.h>
#include <math.h>

#define N_MESH   5151
#define NB       8
#define TT       2048
#define HID      256
#define NLAYERS  3
#define NCHUNK   32
#define CHUNK    64            // TT / NCHUNK
#define NG       101           // threshold grid values 0..100
#define TROW     72            // tab row stride (ushort), 144B = 16B mult
#define NQ       11            // mesh points per thread (11*512 = 5632)
#define NPAD     5632
#define SCAN_GRID 256          // 8 b x 32 c, one block per (b,c)
#define PREP_NBLK 48           // 24576 / 512
#define COPY_NBLK 61           // 123624 / 2048 rounded up
#define MLP_NBLK  81           // 81*64 rows
#define PH2_NBLK  88           // 11 x 8
#define DENSB_NBLK 21          // 41208 / 2048 rounded up

// scan smem layout (bytes): hs2[66] @0, sgv @272, tab @528 (14544)
#define OFF_SGV   272
#define OFF_TAB   528
#define SMEM1     15072
#define OFF_RED   15072        // k3: [64 t][36] floats = 9216
#define OFF_DRED  24288        // k3: [32] floats
#define SMEM3     24416

// ws layout (floats)
#define WS_DENSITY 0           // 5151
#define WS_WT      6144        // 98304 floats (24576 half8)
#define WS_PQ      104448      // NCHUNK*NB*NPAD*2 = 2883584 -> ends 2988032 (~12MB)

// out layout (floats)
#define OUT_BNORM  0           // 16384
#define OUT_DENSB  16384       // 41208
#define OUT_M      57592       // 16384
#define OUT_S0     73976       // 41208
#define OUT_MESHB  115184      // 82416

typedef _Float16 half8  __attribute__((ext_vector_type(8)));
typedef unsigned short u16x8 __attribute__((ext_vector_type(8)));
typedef float    f32x4  __attribute__((ext_vector_type(4)));

__device__ __forceinline__ float sigmoid_fast(float x) {
    float e = __expf(-x);
    return __builtin_amdgcn_rcpf(1.0f + e);
}

// hA byte offset with XOR swizzle (row stride 512 B fp16) -- MLP only
__device__ __forceinline__ int swz(int row, int kbyte) {
    return row * 512 + (kbyte ^ ((row & 7) << 4));
}

// 16-lane sum via DPP (VALU pipe, zero DS ops)
__device__ __forceinline__ float dpp16_sum(float v) {
    int a;
    a = __builtin_amdgcn_update_dpp(0, __float_as_int(v), 0xB1, 0xF, 0xF, true);
    v += __int_as_float(a);
    a = __builtin_amdgcn_update_dpp(0, __float_as_int(v), 0x4E, 0xF, 0xF, true);
    v += __int_as_float(a);
    a = __builtin_amdgcn_update_dpp(0, __float_as_int(v), 0x141, 0xF, 0xF, true);
    v += __int_as_float(a);
    a = __builtin_amdgcn_update_dpp(0, __float_as_int(v), 0x140, 0xF, 0xF, true);
    v += __int_as_float(a);
    return v;
}

// Direction-resolved A-table, [g][t] layout (fp16). 512-thread build.
__device__ __forceinline__ void build_table(int tid, const float* hs2,
                                            float* sgv, unsigned short* tab)
{
    if (tid < CHUNK) sgv[tid] = (hs2[tid + 1] >= hs2[tid]) ? 1.0f : -1.0f;
    for (int idx = tid; idx < NG * CHUNK; idx += 512) {
        int g = idx >> 6;
        int t = idx & 63;
        float ht = hs2[t + 1];
        bool inc = (ht >= hs2[t]);
        float bx = ht * 1000.0f;
        float y = inc ? fmaf(-10.f, (float)g, bx) : fmaf(10.f, (float)g, -bx);
        float A = __builtin_amdgcn_rcpf(1.0f + __expf(y));
        tab[g * TROW + t] = __half_as_ushort(__float2half(A));
    }
}

// phase1 group: update P,R for q in [Q0, Q0+GS) over 8 timesteps
template<int Q0, int GS>
__device__ __forceinline__ void grp_pr(const unsigned short* tab,
    const int (&ga)[NQ], const int (&gb)[NQ], float (&P)[NQ], float (&R)[NQ],
    const float (&sg8)[8], float gstart, int tb)
{
    u16x8 ra[GS], rb[GS];
#pragma unroll
    for (int q = 0; q < GS; ++q) {
        ra[q] = *(const u16x8*)&tab[ga[Q0 + q] * TROW + tb];
        rb[q] = *(const u16x8*)&tab[gb[Q0 + q] * TROW + tb];
    }
    float gp = gstart;
#pragma unroll
    for (int j = 0; j < 8; ++j) {
        float sgt = sg8[j];
        float dl = gp - sgt;
        gp = sgt;
        bool inc = sgt > 0.0f;
#pragma unroll
        for (int q = 0; q < GS; ++q) {
            unsigned short u = inc ? ra[q][j] : rb[q][j];
            float A = __half2float(__ushort_as_half(u));
            float r = R[Q0 + q] + dl;
            P[Q0 + q] *= A;
            R[Q0 + q] = r * A;
        }
    }
}

// phase3 group: update z, accumulate v[8] += sum_q d*z
template<int Q0, int GS>
__device__ __forceinline__ void grp_z(const unsigned short* tab,
    const int (&ga)[NQ], const int (&gb)[NQ], float (&z)[NQ],
    const float (&d)[NQ], const float (&sg8)[8], float (&v)[8],
    float gstart, int tb)
{
    u16x8 ra[GS], rb[GS];
#pragma unroll
    for (int q = 0; q < GS; ++q) {
        ra[q] = *(const u16x8*)&tab[ga[Q0 + q] * TROW + tb];
        rb[q] = *(const u16x8*)&tab[gb[Q0 + q] * TROW + tb];
    }
    float gp = gstart;
#pragma unroll
    for (int j = 0; j < 8; ++j) {
        float sgt = sg8[j];
        float dl = gp - sgt;
        gp = sgt;
        bool inc = sgt > 0.0f;
        float a = 0.f;
#pragma unroll
        for (int q = 0; q < GS; ++q) {
            unsigned short u = inc ? ra[q][j] : rb[q][j];
            float A = __half2float(__ushort_as_half(u));
            float zn = (z[Q0 + q] + dl) * A;
            z[Q0 + q] = zn;
            a = fmaf(d[Q0 + q], zn, a);
        }
        v[j] += a;
    }
}

// ---------------------------------------------------------------------------
// k1: blocks [0,256) phase1 (one per (b,c), all mesh); [256,304) W prep;
//     [304,365) s0/mesh_b copies.
// ---------------------------------------------------------------------------
__global__ __launch_bounds__(512) void k1_scan1_prep(
    const float* __restrict__ dec, const float* __restrict__ y0,
    const float* __restrict__ mesh, const float* __restrict__ Wblk,
    float2* __restrict__ PQ, half8* __restrict__ WT,
    const float* __restrict__ s0, float* __restrict__ out)
{
    __shared__ __align__(16) char smem[SMEM1];
    const int tid = threadIdx.x;
    const int bid = blockIdx.x;

    if (bid >= SCAN_GRID + PREP_NBLK) {
        // ---- s0 / mesh_b copies ----
        int idx = bid - (SCAN_GRID + PREP_NBLK);
        const int n1 = NB * N_MESH;                 // 41208
        const int total = 3 * n1;                   // 123624
#pragma unroll
        for (int k = 0; k < 4; ++k) {
            int j = idx * 2048 + k * 512 + tid;
            if (j < total) {
                if (j < n1) out[OUT_S0 + j] = s0[j];
                else {
                    int jj = j - n1;
                    out[OUT_MESHB + jj] = mesh[jj % (2 * N_MESH)];
                }
            }
        }
        return;
    }

    if (bid >= SCAN_GRID) {
        // ---- prep: gather W into per-lane MFMA fragment order ----
        int g = (bid - SCAN_GRID) * 512 + tid;   // [0, 24576)
        int l  = g & 63;
        int nt = (g >> 6) & 15;
        int kg = (g >> 10) & 7;
        int L  = g >> 13;
        int n  = nt * 16 + (l & 15);
        int kb = kg * 32 + ((l >> 4) & 3) * 8;
        const float* Wb = Wblk + (size_t)L * HID * HID;
        half8 v;
#pragma unroll
        for (int i = 0; i < 8; ++i)
            v[i] = (_Float16)Wb[(size_t)(kb + i) * HID + n];
        WT[g] = v;
        return;
    }

    // ---- phase1 ----
    float* hs2 = (float*)smem;
    float* sgv = (float*)(smem + OFF_SGV);
    unsigned short* tab = (unsigned short*)(smem + OFF_TAB);

    const int b = bid & 7;
    const int c = bid >> 3;
    const int t0 = c * CHUNK;

    if (tid < CHUNK) hs2[tid + 1] = dec[b * TT + t0 + tid];
    if (tid == 0) hs2[0] = (c == 0) ? y0[b] : dec[b * TT + t0 - 1];

    int ga[NQ], gb[NQ];
#pragma unroll
    for (int q = 0; q < NQ; ++q) {
        int n = q * 512 + tid;
        if (n < N_MESH) {
            gb[q] = (int)(mesh[2 * n]     * 100.0f + 0.5f);
            ga[q] = (int)(mesh[2 * n + 1] * 100.0f + 0.5f);
        } else { ga[q] = 0; gb[q] = 0; }
    }
    __syncthreads();
    build_table(tid, hs2, sgv, tab);
    __syncthreads();

    float P[NQ], R[NQ];
    float gprev = sgv[0];
#pragma unroll
    for (int q = 0; q < NQ; ++q) { P[q] = 1.f; R[q] = -gprev; }

    for (int tb = 0; tb < CHUNK; tb += 8) {
        float4 sA = *(const float4*)&sgv[tb];
        float4 sB = *(const float4*)&sgv[tb + 4];
        float sg8[8] = {sA.x, sA.y, sA.z, sA.w, sB.x, sB.y, sB.z, sB.w};
        float gs = gprev;
        grp_pr<0, 4>(tab, ga, gb, P, R, sg8, gs, tb);
        grp_pr<4, 4>(tab, ga, gb, P, R, sg8, gs, tb);
        grp_pr<8, 3>(tab, ga, gb, P, R, sg8, gs, tb);
        gprev = sg8[7];
    }
    size_t basew = ((size_t)(c * NB + b)) * NPAD;
#pragma unroll
    for (int q = 0; q < NQ; ++q) {
        float2 v; v.x = P[q]; v.y = R[q] + gprev;
        PQ[basew + q * 512 + tid] = v;
    }
}

// ---------------------------------------------------------------------------
// k2: blocks [0,81) = MFMA density MLP (proven body); [81,169) = phase2.
// ---------------------------------------------------------------------------
__global__ __launch_bounds__(512) void k2_mlp_phase2(
    const float* __restrict__ mesh, const float* __restrict__ Win,
    const float* __restrict__ bin,  const half8* __restrict__ WT,
    const float* __restrict__ bblk, const float* __restrict__ Wout,
    const float* __restrict__ bout, float* __restrict__ density,
    const float* __restrict__ s0_in, float* __restrict__ PQf)
{
    __shared__ __align__(16) char hA[64 * 512];   // 32 KB
    __shared__ float psum[4][16][2];
    const int tid  = threadIdx.x;

    if (blockIdx.x >= MLP_NBLK) {
        // ---- phase2: boundary states into PQ .x slot ----
        int idx = blockIdx.x - MLP_NBLK;   // 0..87
        int nbb = idx % NQ;
        int b   = idx / NQ;
        int n   = nbb * 512 + tid;
        const float2* PQ = (const float2*)PQf;
        float s = (n < N_MESH) ? s0_in[b * N_MESH + n] : 0.f;
#pragma unroll 4
        for (int c = 0; c < NCHUNK; ++c) {
            size_t ix = ((size_t)(c * NB + b)) * NPAD + n;
            float2 pv = PQ[ix];
            PQf[2 * ix] = s;
            s = fmaf(pv.x, s, pv.y);
        }
        return;
    }

    const int w    = tid >> 6;
    const int lane = tid & 63;
    const int rl   = lane & 15;
    const int cg   = lane >> 4;
    const int mt   = w & 3;
    const int nh   = w >> 2;
    const int row0 = blockIdx.x * 64;

    float hreg[8][4];

    {
        float m0[4], m1[4];
#pragma unroll
        for (int r = 0; r < 4; ++r) {
            int gr = row0 + mt * 16 + cg * 4 + r;
            if (gr < N_MESH) { m0[r] = mesh[2 * gr]; m1[r] = mesh[2 * gr + 1]; }
            else { m0[r] = 0.f; m1[r] = 0.f; }
        }
#pragma unroll
        for (int j = 0; j < 8; ++j) {
            int col = nh * 128 + j * 16 + rl;
            float wa = Win[col], wb = Win[HID + col], bi = bin[col];
#pragma unroll
            for (int r = 0; r < 4; ++r) {
                float v = fmaxf(fmaf(m0[r], wa, fmaf(m1[r], wb, bi)), 0.f);
                hreg[j][r] = v;
                *(_Float16*)(hA + swz(mt * 16 + cg * 4 + r, col * 2)) =
                    (_Float16)v;
            }
        }
    }
    __syncthreads();

    for (int L = 0; L < NLAYERS; ++L) {
        half8 af[8];
#pragma unroll
        for (int kg = 0; kg < 8; ++kg)
            af[kg] = *(const half8*)(hA + swz(mt * 16 + rl, kg * 64 + cg * 16));
        __syncthreads();

        float bias[8];
#pragma unroll
        for (int j = 0; j < 8; ++j)
            bias[j] = bblk[L * HID + nh * 128 + j * 16 + rl];

        f32x4 acc[8];
#pragma unroll
        for (int j = 0; j < 8; ++j) acc[j] = (f32x4){0.f, 0.f, 0.f, 0.f};

        const half8* WTL = WT + ((size_t)(L * 8) * 16 + nh * 8) * 64 + lane;
        half8 b0[8], b1[8];
#pragma unroll
        for (int j = 0; j < 8; ++j) b0[j] = WTL[(size_t)j * 64];
#pragma unroll
        for (int kg2 = 0; kg2 < 8; kg2 += 2) {
#pragma unroll
            for (int j = 0; j < 8; ++j)
                b1[j] = WTL[(size_t)(kg2 + 1) * 1024 + (size_t)j * 64];
#pragma unroll
            for (int j = 0; j < 8; ++j)
                acc[j] = __builtin_amdgcn_mfma_f32_16x16x32_f16(
                    af[kg2], b0[j], acc[j], 0, 0, 0);
            if (kg2 + 2 < 8) {
#pragma unroll
                for (int j = 0; j < 8; ++j)
                    b0[j] = WTL[(size_t)(kg2 + 2) * 1024 + (size_t)j * 64];
            }
#pragma unroll
            for (int j = 0; j < 8; ++j)
                acc[j] = __builtin_amdgcn_mfma_f32_16x16x32_f16(
                    af[kg2 + 1], b1[j], acc[j], 0, 0, 0);
        }

#pragma unroll
        for (int j = 0; j < 8; ++j) {
            int col = nh * 128 + j * 16 + rl;
#pragma unroll
            for (int r = 0; r < 4; ++r) {
                float v = hreg[j][r] + fmaxf(acc[j][r] + bias[j], 0.f);
                hreg[j][r] = v;
                if (L < NLAYERS - 1)
                    *(_Float16*)(hA + swz(mt * 16 + cg * 4 + r, col * 2)) =
                        (_Float16)v;
            }
        }
        if (L < NLAYERS - 1) __syncthreads();
    }

    {
        float p[4] = {0.f, 0.f, 0.f, 0.f};
#pragma unroll
        for (int j = 0; j < 8; ++j) {
            float wo = Wout[nh * 128 + j * 16 + rl];
#pragma unroll
            for (int r = 0; r < 4; ++r) p[r] = fmaf(hreg[j][r], wo, p[r]);
        }
#pragma unroll
        for (int st = 1; st < 16; st <<= 1)
#pragma unroll
            for (int r = 0; r < 4; ++r) p[r] += __shfl_xor(p[r], st, 64);
        if (rl == 0) {
#pragma unroll
            for (int r = 0; r < 4; ++r) psum[mt][cg * 4 + r][nh] = p[r];
        }
    }
    __syncthreads();
    if (tid < 64) {
        int gr = row0 + tid;
        float pp = psum[tid >> 4][tid & 15][0] + psum[tid >> 4][tid & 15][1];
        if (gr < N_MESH) density[gr] = sigmoid_fast(pp + bout[0]);
    }
}

// ---------------------------------------------------------------------------
// k3: blocks [0,256) phase3 + in-block finalize (m, b_norm);
//     blocks [256,277) density_b copy.
// ---------------------------------------------------------------------------
__global__ __launch_bounds__(512) void k3_phase3_fin(
    const float* __restrict__ dec, const float* __restrict__ y0,
    const float* __restrict__ mesh, const float* __restrict__ density,
    const float* __restrict__ PQf, float* __restrict__ out)
{
    __shared__ __align__(16) char smem[SMEM3];
    const int tid = threadIdx.x;
    const int bid = blockIdx.x;

    if (bid >= SCAN_GRID) {
        // ---- density_b copy ----
        int idx = bid - SCAN_GRID;
#pragma unroll
        for (int k = 0; k < 4; ++k) {
            int j = idx * 2048 + k * 512 + tid;
            if (j < NB * N_MESH) out[OUT_DENSB + j] = density[j % N_MESH];
        }
        return;
    }

    float* hs2 = (float*)smem;
    float* sgv = (float*)(smem + OFF_SGV);
    unsigned short* tab = (unsigned short*)(smem + OFF_TAB);
    float* red  = (float*)(smem + OFF_RED);    // [64 t][36]
    float* Dred = (float*)(smem + OFF_DRED);   // [32]

    const int b = bid & 7;
    const int c = bid >> 3;
    const int t0 = c * CHUNK;

    if (tid < CHUNK) hs2[tid + 1] = dec[b * TT + t0 + tid];
    if (tid == 0) hs2[0] = (c == 0) ? y0[b] : dec[b * TT + t0 - 1];

    int ga[NQ], gb[NQ];
    float d[NQ], S[NQ];
#pragma unroll
    for (int q = 0; q < NQ; ++q) {
        int n = q * 512 + tid;
        if (n < N_MESH) {
            gb[q] = (int)(mesh[2 * n]     * 100.0f + 0.5f);
            ga[q] = (int)(mesh[2 * n + 1] * 100.0f + 0.5f);
            d[q]  = density[n];
            S[q]  = PQf[2 * (((size_t)(c * NB + b)) * NPAD + n)];
        } else { ga[q] = 0; gb[q] = 0; d[q] = 0.f; S[q] = 0.f; }
    }
    // block-local D = sum(density) (identical order in every block)
    {
        float Dp = 0.f;
#pragma unroll
        for (int q = 0; q < NQ; ++q) Dp += d[q];
        Dp = dpp16_sum(Dp);
        if ((tid & 15) == 0) Dred[tid >> 4] = Dp;
    }
    __syncthreads();
    build_table(tid, hs2, sgv, tab);
    __syncthreads();

    float z[NQ];
    float gprev = sgv[0];
#pragma unroll
    for (int q = 0; q < NQ; ++q) z[q] = S[q] - gprev;

    for (int tb = 0; tb < CHUNK; tb += 8) {
        float4 sA = *(const float4*)&sgv[tb];
        float4 sB = *(const float4*)&sgv[tb + 4];
        float sg8[8] = {sA.x, sA.y, sA.z, sA.w, sB.x, sB.y, sB.z, sB.w};
        float v[8] = {0.f, 0.f, 0.f, 0.f, 0.f, 0.f, 0.f, 0.f};
        float gs = gprev;
        grp_z<0, 4>(tab, ga, gb, z, d, sg8, v, gs, tb);
        grp_z<4, 4>(tab, ga, gb, z, d, sg8, v, gs, tb);
        grp_z<8, 3>(tab, ga, gb, z, d, sg8, v, gs, tb);
        gprev = sg8[7];

#pragma unroll
        for (int j = 0; j < 8; ++j) v[j] = dpp16_sum(v[j]);
        float outv = v[0];
#pragma unroll
        for (int j = 1; j < 8; ++j) if ((tid & 15) == j) outv = v[j];
        if ((tid & 15) < 8)
            red[(tb + (tid & 15)) * 36 + (tid >> 4)] = outv;
    }
    __syncthreads();

    // finalize: 64 threads, one per t in this chunk
    if (tid < CHUNK) {
        float acc = 0.f;
#pragma unroll
        for (int g4 = 0; g4 < 32; g4 += 4) {
            float4 r4 = *(const float4*)&red[tid * 36 + g4];
            acc += (r4.x + r4.y) + (r4.z + r4.w);
        }
        float D = 0.f;
#pragma unroll
        for (int g4 = 0; g4 < 32; g4 += 4) {
            float4 d4 = *(const float4*)&Dred[g4];
            D += (d4.x + d4.y) + (d4.z + d4.w);
        }
        float gd = sgv[tid];                 // direction sign at t
        int t = t0 + tid;
        float m = (acc + gd * D) / D;
        out[OUT_M + b * TT + t] = m;
        out[OUT_BNORM + b * TT + t] = 0.5f * m + 0.5f;
    }
}

extern "C" void kernel_launch(void* const* d_in, const int* in_sizes, int n_in,
                              void* d_out, int out_size, void* d_ws, size_t ws_size,
                              hipStream_t stream) {
    const float* dec  = (const float*)d_in[1];
    const float* s0   = (const float*)d_in[2];
    const float* y0   = (const float*)d_in[3];
    const float* mesh = (const float*)d_in[4];
    const float* Win  = (const float*)d_in[5];
    const float* bin  = (const float*)d_in[6];
    const float* Wblk = (const float*)d_in[7];
    const float* bblk = (const float*)d_in[8];
    const float* Wout = (const float*)d_in[9];
    const float* bout = (const float*)d_in[10];
    float* out = (float*)d_out;
    float* ws  = (float*)d_ws;

    float*  density  = ws + WS_DENSITY;
    half8*  wt       = (half8*)(ws + WS_WT);
    float*  pqf      = ws + WS_PQ;
    float2* pq       = (float2*)pqf;

    k1_scan1_prep<<<SCAN_GRID + PREP_NBLK + COPY_NBLK, 512, 0, stream>>>(
        dec, y0, mesh, Wblk, pq, wt, s0, out);
    k2_mlp_phase2<<<MLP_NBLK + PH2_NBLK, 512, 0, stream>>>(
        mesh, Win, bin, wt, bblk, Wout, bout, density, s0, pqf);
    k3_phase3_fin<<<SCAN_GRID + DENSB_NBLK, 512, 0, stream>>>(
        dec, y0, mesh, density, pqf, out);
}

// Round 17
// 74.060 us; speedup vs baseline: 2.1892x; 1.0045x over previous
//
#include <hip/hip_runtime.h>
#include <hip/hip_fp16.h>
#include <math.h>

#define N_MESH   5151
#define NB       8
#define TT       2048
#define HID      256
#define NLAYERS  3
#define NCHUNK   64
#define CHUNK    32            // TT / NCHUNK
#define NG       101           // threshold grid values 0..100
#define TROW     40            // tab row stride (ushort), 80 B (16B mult, bank-spread)
#define NQ       11            // mesh points per thread (11*512 = 5632)
#define NPAD     5632
#define SCAN_GRID 512          // 8 b x 64 c, one block per (b,c)
#define PREP_NBLK 48           // 24576 / 512
#define COPY_NBLK 61           // 123624 / 2048 rounded up
#define MLP_NBLK  81           // 81*64 rows
#define PH2_NBLK  88           // 11 x 8
#define DENSB_NBLK 21          // 41208 / 2048 rounded up

// scan smem layout (bytes): hs2[36] @0, sgv[32] @144, tab @272 (8080)
#define OFF_SGV   144
#define OFF_TAB   272
#define SMEM1     8352
#define OFF_RED   8352         // k3: [32 t][36] floats = 4608
#define OFF_DRED  12960        // k3: [32] floats
#define SMEM3     13088

// ws layout (floats)
#define WS_DENSITY 0           // 5151
#define WS_WT      6144        // 98304 floats (24576 half8)
#define WS_PQ      104448      // NCHUNK*NB*NPAD*2 = 5767168 -> ends 5871616 (~23MB)

// out layout (floats)
#define OUT_BNORM  0           // 16384
#define OUT_DENSB  16384       // 41208
#define OUT_M      57592       // 16384
#define OUT_S0     73976       // 41208
#define OUT_MESHB  115184      // 82416

typedef _Float16 half8  __attribute__((ext_vector_type(8)));
typedef unsigned short u16x8 __attribute__((ext_vector_type(8)));
typedef float    f32x4  __attribute__((ext_vector_type(4)));

__device__ __forceinline__ float sigmoid_fast(float x) {
    float e = __expf(-x);
    return __builtin_amdgcn_rcpf(1.0f + e);
}

// hA byte offset with XOR swizzle (row stride 512 B fp16) -- MLP only
__device__ __forceinline__ int swz(int row, int kbyte) {
    return row * 512 + (kbyte ^ ((row & 7) << 4));
}

// 16-lane sum via DPP (VALU pipe, zero DS ops)
__device__ __forceinline__ float dpp16_sum(float v) {
    int a;
    a = __builtin_amdgcn_update_dpp(0, __float_as_int(v), 0xB1, 0xF, 0xF, true);
    v += __int_as_float(a);
    a = __builtin_amdgcn_update_dpp(0, __float_as_int(v), 0x4E, 0xF, 0xF, true);
    v += __int_as_float(a);
    a = __builtin_amdgcn_update_dpp(0, __float_as_int(v), 0x141, 0xF, 0xF, true);
    v += __int_as_float(a);
    a = __builtin_amdgcn_update_dpp(0, __float_as_int(v), 0x140, 0xF, 0xF, true);
    v += __int_as_float(a);
    return v;
}

// Direction-resolved A-table, [g][t] layout (fp16). 512-thread build.
__device__ __forceinline__ void build_table(int tid, const float* hs2,
                                            float* sgv, unsigned short* tab)
{
    if (tid < CHUNK) sgv[tid] = (hs2[tid + 1] >= hs2[tid]) ? 1.0f : -1.0f;
    for (int idx = tid; idx < NG * CHUNK; idx += 512) {
        int g = idx >> 5;          // CHUNK = 32
        int t = idx & 31;
        float ht = hs2[t + 1];
        bool inc = (ht >= hs2[t]);
        float bx = ht * 1000.0f;
        float y = inc ? fmaf(-10.f, (float)g, bx) : fmaf(10.f, (float)g, -bx);
        float A = __builtin_amdgcn_rcpf(1.0f + __expf(y));
        tab[g * TROW + t] = __half_as_ushort(__float2half(A));
    }
}

// phase1 group: update P,R for q in [Q0, Q0+GS) over 8 timesteps
template<int Q0, int GS>
__device__ __forceinline__ void grp_pr(const unsigned short* tab,
    const int (&ga)[NQ], const int (&gb)[NQ], float (&P)[NQ], float (&R)[NQ],
    const float (&sg8)[8], float gstart, int tb)
{
    u16x8 ra[GS], rb[GS];
#pragma unroll
    for (int q = 0; q < GS; ++q) {
        ra[q] = *(const u16x8*)&tab[ga[Q0 + q] * TROW + tb];
        rb[q] = *(const u16x8*)&tab[gb[Q0 + q] * TROW + tb];
    }
    float gp = gstart;
#pragma unroll
    for (int j = 0; j < 8; ++j) {
        float sgt = sg8[j];
        float dl = gp - sgt;
        gp = sgt;
        bool inc = sgt > 0.0f;
#pragma unroll
        for (int q = 0; q < GS; ++q) {
            unsigned short u = inc ? ra[q][j] : rb[q][j];
            float A = __half2float(__ushort_as_half(u));
            float r = R[Q0 + q] + dl;
            P[Q0 + q] *= A;
            R[Q0 + q] = r * A;
        }
    }
}

// phase3 group: update z, accumulate v[8] += sum_q d*z
template<int Q0, int GS>
__device__ __forceinline__ void grp_z(const unsigned short* tab,
    const int (&ga)[NQ], const int (&gb)[NQ], float (&z)[NQ],
    const float (&d)[NQ], const float (&sg8)[8], float (&v)[8],
    float gstart, int tb)
{
    u16x8 ra[GS], rb[GS];
#pragma unroll
    for (int q = 0; q < GS; ++q) {
        ra[q] = *(const u16x8*)&tab[ga[Q0 + q] * TROW + tb];
        rb[q] = *(const u16x8*)&tab[gb[Q0 + q] * TROW + tb];
    }
    float gp = gstart;
#pragma unroll
    for (int j = 0; j < 8; ++j) {
        float sgt = sg8[j];
        float dl = gp - sgt;
        gp = sgt;
        bool inc = sgt > 0.0f;
        float a = 0.f;
#pragma unroll
        for (int q = 0; q < GS; ++q) {
            unsigned short u = inc ? ra[q][j] : rb[q][j];
            float A = __half2float(__ushort_as_half(u));
            float zn = (z[Q0 + q] + dl) * A;
            z[Q0 + q] = zn;
            a = fmaf(d[Q0 + q], zn, a);
        }
        v[j] += a;
    }
}

// ---------------------------------------------------------------------------
// k1: blocks [0,512) phase1 (one per (b,c), all mesh); [512,560) W prep;
//     [560,621) s0/mesh_b copies.
// ---------------------------------------------------------------------------
__global__ __launch_bounds__(512, 4) void k1_scan1_prep(
    const float* __restrict__ dec, const float* __restrict__ y0,
    const float* __restrict__ mesh, const float* __restrict__ Wblk,
    float2* __restrict__ PQ, half8* __restrict__ WT,
    const float* __restrict__ s0, float* __restrict__ out)
{
    __shared__ __align__(16) char smem[SMEM1];
    const int tid = threadIdx.x;
    const int bid = blockIdx.x;

    if (bid >= SCAN_GRID + PREP_NBLK) {
        // ---- s0 / mesh_b copies ----
        int idx = bid - (SCAN_GRID + PREP_NBLK);
        const int n1 = NB * N_MESH;                 // 41208
        const int total = 3 * n1;                   // 123624
#pragma unroll
        for (int k = 0; k < 4; ++k) {
            int j = idx * 2048 + k * 512 + tid;
            if (j < total) {
                if (j < n1) out[OUT_S0 + j] = s0[j];
                else {
                    int jj = j - n1;
                    out[OUT_MESHB + jj] = mesh[jj % (2 * N_MESH)];
                }
            }
        }
        return;
    }

    if (bid >= SCAN_GRID) {
        // ---- prep: gather W into per-lane MFMA fragment order ----
        int g = (bid - SCAN_GRID) * 512 + tid;   // [0, 24576)
        int l  = g & 63;
        int nt = (g >> 6) & 15;
        int kg = (g >> 10) & 7;
        int L  = g >> 13;
        int n  = nt * 16 + (l & 15);
        int kb = kg * 32 + ((l >> 4) & 3) * 8;
        const float* Wb = Wblk + (size_t)L * HID * HID;
        half8 v;
#pragma unroll
        for (int i = 0; i < 8; ++i)
            v[i] = (_Float16)Wb[(size_t)(kb + i) * HID + n];
        WT[g] = v;
        return;
    }

    // ---- phase1 ----
    float* hs2 = (float*)smem;
    float* sgv = (float*)(smem + OFF_SGV);
    unsigned short* tab = (unsigned short*)(smem + OFF_TAB);

    const int b = bid & 7;
    const int c = bid >> 3;
    const int t0 = c * CHUNK;

    if (tid < CHUNK) hs2[tid + 1] = dec[b * TT + t0 + tid];
    if (tid == 0) hs2[0] = (c == 0) ? y0[b] : dec[b * TT + t0 - 1];

    int ga[NQ], gb[NQ];
#pragma unroll
    for (int q = 0; q < NQ; ++q) {
        int n = q * 512 + tid;
        if (n < N_MESH) {
            gb[q] = (int)(mesh[2 * n]     * 100.0f + 0.5f);
            ga[q] = (int)(mesh[2 * n + 1] * 100.0f + 0.5f);
        } else { ga[q] = 0; gb[q] = 0; }
    }
    __syncthreads();
    build_table(tid, hs2, sgv, tab);
    __syncthreads();

    float P[NQ], R[NQ];
    float gprev = sgv[0];
#pragma unroll
    for (int q = 0; q < NQ; ++q) { P[q] = 1.f; R[q] = -gprev; }

    for (int tb = 0; tb < CHUNK; tb += 8) {
        float4 sA = *(const float4*)&sgv[tb];
        float4 sB = *(const float4*)&sgv[tb + 4];
        float sg8[8] = {sA.x, sA.y, sA.z, sA.w, sB.x, sB.y, sB.z, sB.w};
        float gs = gprev;
        grp_pr<0, 4>(tab, ga, gb, P, R, sg8, gs, tb);
        grp_pr<4, 4>(tab, ga, gb, P, R, sg8, gs, tb);
        grp_pr<8, 3>(tab, ga, gb, P, R, sg8, gs, tb);
        gprev = sg8[7];
    }
    size_t basew = ((size_t)(c * NB + b)) * NPAD;
#pragma unroll
    for (int q = 0; q < NQ; ++q) {
        float2 v; v.x = P[q]; v.y = R[q] + gprev;
        PQ[basew + q * 512 + tid] = v;
    }
}

// ---------------------------------------------------------------------------
// k2: blocks [0,81) = MFMA density MLP (proven body); [81,169) = phase2.
// ---------------------------------------------------------------------------
__global__ __launch_bounds__(512) void k2_mlp_phase2(
    const float* __restrict__ mesh, const float* __restrict__ Win,
    const float* __restrict__ bin,  const half8* __restrict__ WT,
    const float* __restrict__ bblk, const float* __restrict__ Wout,
    const float* __restrict__ bout, float* __restrict__ density,
    const float* __restrict__ s0_in, float* __restrict__ PQf)
{
    __shared__ __align__(16) char hA[64 * 512];   // 32 KB
    __shared__ float psum[4][16][2];
    const int tid  = threadIdx.x;

    if (blockIdx.x >= MLP_NBLK) {
        // ---- phase2: boundary states into PQ .x slot ----
        int idx = blockIdx.x - MLP_NBLK;   // 0..87
        int nbb = idx % NQ;
        int b   = idx / NQ;
        int n   = nbb * 512 + tid;
        const float2* PQ = (const float2*)PQf;
        float s = (n < N_MESH) ? s0_in[b * N_MESH + n] : 0.f;
#pragma unroll 4
        for (int c = 0; c < NCHUNK; ++c) {
            size_t ix = ((size_t)(c * NB + b)) * NPAD + n;
            float2 pv = PQ[ix];
            PQf[2 * ix] = s;
            s = fmaf(pv.x, s, pv.y);
        }
        return;
    }

    const int w    = tid >> 6;
    const int lane = tid & 63;
    const int rl   = lane & 15;
    const int cg   = lane >> 4;
    const int mt   = w & 3;
    const int nh   = w >> 2;
    const int row0 = blockIdx.x * 64;

    float hreg[8][4];

    {
        float m0[4], m1[4];
#pragma unroll
        for (int r = 0; r < 4; ++r) {
            int gr = row0 + mt * 16 + cg * 4 + r;
            if (gr < N_MESH) { m0[r] = mesh[2 * gr]; m1[r] = mesh[2 * gr + 1]; }
            else { m0[r] = 0.f; m1[r] = 0.f; }
        }
#pragma unroll
        for (int j = 0; j < 8; ++j) {
            int col = nh * 128 + j * 16 + rl;
            float wa = Win[col], wb = Win[HID + col], bi = bin[col];
#pragma unroll
            for (int r = 0; r < 4; ++r) {
                float v = fmaxf(fmaf(m0[r], wa, fmaf(m1[r], wb, bi)), 0.f);
                hreg[j][r] = v;
                *(_Float16*)(hA + swz(mt * 16 + cg * 4 + r, col * 2)) =
                    (_Float16)v;
            }
        }
    }
    __syncthreads();

    for (int L = 0; L < NLAYERS; ++L) {
        half8 af[8];
#pragma unroll
        for (int kg = 0; kg < 8; ++kg)
            af[kg] = *(const half8*)(hA + swz(mt * 16 + rl, kg * 64 + cg * 16));
        __syncthreads();

        float bias[8];
#pragma unroll
        for (int j = 0; j < 8; ++j)
            bias[j] = bblk[L * HID + nh * 128 + j * 16 + rl];

        f32x4 acc[8];
#pragma unroll
        for (int j = 0; j < 8; ++j) acc[j] = (f32x4){0.f, 0.f, 0.f, 0.f};

        const half8* WTL = WT + ((size_t)(L * 8) * 16 + nh * 8) * 64 + lane;
        half8 b0[8], b1[8];
#pragma unroll
        for (int j = 0; j < 8; ++j) b0[j] = WTL[(size_t)j * 64];
#pragma unroll
        for (int kg2 = 0; kg2 < 8; kg2 += 2) {
#pragma unroll
            for (int j = 0; j < 8; ++j)
                b1[j] = WTL[(size_t)(kg2 + 1) * 1024 + (size_t)j * 64];
#pragma unroll
            for (int j = 0; j < 8; ++j)
                acc[j] = __builtin_amdgcn_mfma_f32_16x16x32_f16(
                    af[kg2], b0[j], acc[j], 0, 0, 0);
            if (kg2 + 2 < 8) {
#pragma unroll
                for (int j = 0; j < 8; ++j)
                    b0[j] = WTL[(size_t)(kg2 + 2) * 1024 + (size_t)j * 64];
            }
#pragma unroll
            for (int j = 0; j < 8; ++j)
                acc[j] = __builtin_amdgcn_mfma_f32_16x16x32_f16(
                    af[kg2 + 1], b1[j], acc[j], 0, 0, 0);
        }

#pragma unroll
        for (int j = 0; j < 8; ++j) {
            int col = nh * 128 + j * 16 + rl;
#pragma unroll
            for (int r = 0; r < 4; ++r) {
                float v = hreg[j][r] + fmaxf(acc[j][r] + bias[j], 0.f);
                hreg[j][r] = v;
                if (L < NLAYERS - 1)
                    *(_Float16*)(hA + swz(mt * 16 + cg * 4 + r, col * 2)) =
                        (_Float16)v;
            }
        }
        if (L < NLAYERS - 1) __syncthreads();
    }

    {
        float p[4] = {0.f, 0.f, 0.f, 0.f};
#pragma unroll
        for (int j = 0; j < 8; ++j) {
            float wo = Wout[nh * 128 + j * 16 + rl];
#pragma unroll
            for (int r = 0; r < 4; ++r) p[r] = fmaf(hreg[j][r], wo, p[r]);
        }
#pragma unroll
        for (int st = 1; st < 16; st <<= 1)
#pragma unroll
            for (int r = 0; r < 4; ++r) p[r] += __shfl_xor(p[r], st, 64);
        if (rl == 0) {
#pragma unroll
            for (int r = 0; r < 4; ++r) psum[mt][cg * 4 + r][nh] = p[r];
        }
    }
    __syncthreads();
    if (tid < 64) {
        int gr = row0 + tid;
        float pp = psum[tid >> 4][tid & 15][0] + psum[tid >> 4][tid & 15][1];
        if (gr < N_MESH) density[gr] = sigmoid_fast(pp + bout[0]);
    }
}

// ---------------------------------------------------------------------------
// k3: blocks [0,512) phase3 + in-block finalize (m, b_norm);
//     blocks [512,533) density_b copy.
// ---------------------------------------------------------------------------
__global__ __launch_bounds__(512, 4) void k3_phase3_fin(
    const float* __restrict__ dec, const float* __restrict__ y0,
    const float* __restrict__ mesh, const float* __restrict__ density,
    const float* __restrict__ PQf, float* __restrict__ out)
{
    __shared__ __align__(16) char smem[SMEM3];
    const int tid = threadIdx.x;
    const int bid = blockIdx.x;

    if (bid >= SCAN_GRID) {
        // ---- density_b copy ----
        int idx = bid - SCAN_GRID;
#pragma unroll
        for (int k = 0; k < 4; ++k) {
            int j = idx * 2048 + k * 512 + tid;
            if (j < NB * N_MESH) out[OUT_DENSB + j] = density[j % N_MESH];
        }
        return;
    }

    float* hs2 = (float*)smem;
    float* sgv = (float*)(smem + OFF_SGV);
    unsigned short* tab = (unsigned short*)(smem + OFF_TAB);
    float* red  = (float*)(smem + OFF_RED);    // [32 t][36]
    float* Dred = (float*)(smem + OFF_DRED);   // [32]

    const int b = bid & 7;
    const int c = bid >> 3;
    const int t0 = c * CHUNK;

    if (tid < CHUNK) hs2[tid + 1] = dec[b * TT + t0 + tid];
    if (tid == 0) hs2[0] = (c == 0) ? y0[b] : dec[b * TT + t0 - 1];

    int ga[NQ], gb[NQ];
    float d[NQ], S[NQ];
#pragma unroll
    for (int q = 0; q < NQ; ++q) {
        int n = q * 512 + tid;
        if (n < N_MESH) {
            gb[q] = (int)(mesh[2 * n]     * 100.0f + 0.5f);
            ga[q] = (int)(mesh[2 * n + 1] * 100.0f + 0.5f);
            d[q]  = density[n];
            S[q]  = PQf[2 * (((size_t)(c * NB + b)) * NPAD + n)];
        } else { ga[q] = 0; gb[q] = 0; d[q] = 0.f; S[q] = 0.f; }
    }
    // block-local D = sum(density) (identical order in every block)
    {
        float Dp = 0.f;
#pragma unroll
        for (int q = 0; q < NQ; ++q) Dp += d[q];
        Dp = dpp16_sum(Dp);
        if ((tid & 15) == 0) Dred[tid >> 4] = Dp;
    }
    __syncthreads();
    build_table(tid, hs2, sgv, tab);
    __syncthreads();

    float z[NQ];
    float gprev = sgv[0];
#pragma unroll
    for (int q = 0; q < NQ; ++q) z[q] = S[q] - gprev;

    for (int tb = 0; tb < CHUNK; tb += 8) {
        float4 sA = *(const float4*)&sgv[tb];
        float4 sB = *(const float4*)&sgv[tb + 4];
        float sg8[8] = {sA.x, sA.y, sA.z, sA.w, sB.x, sB.y, sB.z, sB.w};
        float v[8] = {0.f, 0.f, 0.f, 0.f, 0.f, 0.f, 0.f, 0.f};
        float gs = gprev;
        grp_z<0, 4>(tab, ga, gb, z, d, sg8, v, gs, tb);
        grp_z<4, 4>(tab, ga, gb, z, d, sg8, v, gs, tb);
        grp_z<8, 3>(tab, ga, gb, z, d, sg8, v, gs, tb);
        gprev = sg8[7];

#pragma unroll
        for (int j = 0; j < 8; ++j) v[j] = dpp16_sum(v[j]);
        float outv = v[0];
#pragma unroll
        for (int j = 1; j < 8; ++j) if ((tid & 15) == j) outv = v[j];
        if ((tid & 15) < 8)
            red[(tb + (tid & 15)) * 36 + (tid >> 4)] = outv;
    }
    __syncthreads();

    // finalize: 32 threads, one per t in this chunk
    if (tid < CHUNK) {
        float acc = 0.f;
#pragma unroll
        for (int g4 = 0; g4 < 32; g4 += 4) {
            float4 r4 = *(const float4*)&red[tid * 36 + g4];
            acc += (r4.x + r4.y) + (r4.z + r4.w);
        }
        float D = 0.f;
#pragma unroll
        for (int g4 = 0; g4 < 32; g4 += 4) {
            float4 d4 = *(const float4*)&Dred[g4];
            D += (d4.x + d4.y) + (d4.z + d4.w);
        }
        float gd = sgv[tid];                 // direction sign at t
        int t = t0 + tid;
        float m = (acc + gd * D) / D;
        out[OUT_M + b * TT + t] = m;
        out[OUT_BNORM + b * TT + t] = 0.5f * m + 0.5f;
    }
}

extern "C" void kernel_launch(void* const* d_in, const int* in_sizes, int n_in,
                              void* d_out, int out_size, void* d_ws, size_t ws_size,
                              hipStream_t stream) {
    const float* dec  = (const float*)d_in[1];
    const float* s0   = (const float*)d_in[2];
    const float* y0   = (const float*)d_in[3];
    const float* mesh = (const float*)d_in[4];
    const float* Win  = (const float*)d_in[5];
    const float* bin  = (const float*)d_in[6];
    const float* Wblk = (const float*)d_in[7];
    const float* bblk = (const float*)d_in[8];
    const float* Wout = (const float*)d_in[9];
    const float* bout = (const float*)d_in[10];
    float* out = (float*)d_out;
    float* ws  = (float*)d_ws;

    float*  density  = ws + WS_DENSITY;
    half8*  wt       = (half8*)(ws + WS_WT);
    float*  pqf      = ws + WS_PQ;
    float2* pq       = (float2*)pqf;

    k1_scan1_prep<<<SCAN_GRID + PREP_NBLK + COPY_NBLK, 512, 0, stream>>>(
        dec, y0, mesh, Wblk, pq, wt, s0, out);
    k2_mlp_phase2<<<MLP_NBLK + PH2_NBLK, 512, 0, stream>>>(
        mesh, Win, bin, wt, bblk, Wout, bout, density, s0, pqf);
    k3_phase3_fin<<<SCAN_GRID + DENSB_NBLK, 512, 0, stream>>>(
        dec, y0, mesh, density, pqf, out);
}

// Round 18
// 67.067 us; speedup vs baseline: 2.4175x; 1.1043x over previous
//
#include <hip/hip_runtime.h>
#include <hip/hip_fp16.h>
#include <math.h>

#define N_MESH   5151
#define NB       8
#define TT       2048
#define HID      256
#define NLAYERS  3
#define NCHUNK   64
#define CHUNK    32            // TT / NCHUNK
#define NQ       11            // mesh points per thread (11*512 = 5632)
#define NPAD     5632
#define SCAN_GRID 512          // 8 b x 64 c, one block per (b,c)
#define PREP_NBLK 48           // 24576 / 512
#define COPY_NBLK 61           // 123624 / 2048 rounded up
#define MLP_NBLK  81           // 81*64 rows
#define PH2_NBLK  88           // 11 x 8
#define DENSB_NBLK 21          // 41208 / 2048 rounded up

// scan smem layout (bytes): hs2[34] @0 (pad to 144), tp[32] float4 @144
#define OFF_TP    144
#define SMEM1     656
#define OFF_RED   656          // k3: [32 t][36] floats = 4608
#define OFF_DRED  5264         // k3: [32] floats
#define SMEM3     5392

// ws layout (floats)
#define WS_DENSITY 0           // 5151
#define WS_WT      6144        // 98304 floats (24576 half8)
#define WS_PQ      104448      // NCHUNK*NB*NPAD*2 = 5767168 -> ends 5871616 (~23MB)

// out layout (floats)
#define OUT_BNORM  0           // 16384
#define OUT_DENSB  16384       // 41208
#define OUT_M      57592       // 16384
#define OUT_S0     73976       // 41208
#define OUT_MESHB  115184      // 82416

typedef _Float16 half8  __attribute__((ext_vector_type(8)));
typedef float    f32x4  __attribute__((ext_vector_type(4)));

__device__ __forceinline__ float sigmoid_fast(float x) {
    float e = __expf(-x);
    return __builtin_amdgcn_rcpf(1.0f + e);
}

// hA byte offset with XOR swizzle (row stride 512 B fp16) -- MLP only
__device__ __forceinline__ int swz(int row, int kbyte) {
    return row * 512 + (kbyte ^ ((row & 7) << 4));
}

// 16-lane sum via DPP (VALU pipe, zero DS ops)
__device__ __forceinline__ float dpp16_sum(float v) {
    int a;
    a = __builtin_amdgcn_update_dpp(0, __float_as_int(v), 0xB1, 0xF, 0xF, true);
    v += __int_as_float(a);
    a = __builtin_amdgcn_update_dpp(0, __float_as_int(v), 0x4E, 0xF, 0xF, true);
    v += __int_as_float(a);
    a = __builtin_amdgcn_update_dpp(0, __float_as_int(v), 0x141, 0xF, 0xF, true);
    v += __int_as_float(a);
    a = __builtin_amdgcn_update_dpp(0, __float_as_int(v), 0x140, 0xF, 0xF, true);
    v += __int_as_float(a);
    return v;
}

// Per-t wave-uniform params: {dl, u, v, sg}.
// A(g) = med3(u*g + v, 0, 1) reproduces the direction-resolved sigmoid:
// inc: u=+1, v = Acrit - gc ; dec: u=-1, v = gc + Acrit, gc = round(100*h_t).
__device__ __forceinline__ void build_params(int tid, const float* hs2,
                                             float4* tp)
{
    if (tid < CHUNK) {
        float ht = hs2[tid + 1];
        float hp = hs2[tid];
        bool inc = (ht >= hp);
        float sg = inc ? 1.f : -1.f;
        float psg = sg;
        if (tid > 0) psg = (hs2[tid] >= hs2[tid - 1]) ? 1.f : -1.f;
        float x = ht * 1000.f;
        float gc = rintf(ht * 100.f);
        float4 p;
        p.x = psg - sg;                       // dl (0 or +-2)
        if (inc) {
            float Ac = sigmoid_fast(fmaf(10.f, gc, -x));
            p.y = 1.f;  p.z = Ac - gc;
        } else {
            float Ac = sigmoid_fast(fmaf(-10.f, gc, x));
            p.y = -1.f; p.z = gc + Ac;
        }
        p.w = sg;
        tp[tid] = p;
    }
}

// ---------------------------------------------------------------------------
// k1: blocks [0,512) phase1 (one per (b,c), all mesh); [512,560) W prep;
//     [560,621) s0/mesh_b copies.
// ---------------------------------------------------------------------------
__global__ __launch_bounds__(512, 4) void k1_scan1_prep(
    const float* __restrict__ dec, const float* __restrict__ y0,
    const float* __restrict__ mesh, const float* __restrict__ Wblk,
    float2* __restrict__ PQ, half8* __restrict__ WT,
    const float* __restrict__ s0, float* __restrict__ out)
{
    __shared__ __align__(16) char smem[SMEM1];
    const int tid = threadIdx.x;
    const int bid = blockIdx.x;

    if (bid >= SCAN_GRID + PREP_NBLK) {
        // ---- s0 / mesh_b copies ----
        int idx = bid - (SCAN_GRID + PREP_NBLK);
        const int n1 = NB * N_MESH;                 // 41208
        const int total = 3 * n1;                   // 123624
#pragma unroll
        for (int k = 0; k < 4; ++k) {
            int j = idx * 2048 + k * 512 + tid;
            if (j < total) {
                if (j < n1) out[OUT_S0 + j] = s0[j];
                else {
                    int jj = j - n1;
                    out[OUT_MESHB + jj] = mesh[jj % (2 * N_MESH)];
                }
            }
        }
        return;
    }

    if (bid >= SCAN_GRID) {
        // ---- prep: gather W into per-lane MFMA fragment order ----
        int g = (bid - SCAN_GRID) * 512 + tid;   // [0, 24576)
        int l  = g & 63;
        int nt = (g >> 6) & 15;
        int kg = (g >> 10) & 7;
        int L  = g >> 13;
        int n  = nt * 16 + (l & 15);
        int kb = kg * 32 + ((l >> 4) & 3) * 8;
        const float* Wb = Wblk + (size_t)L * HID * HID;
        half8 v;
#pragma unroll
        for (int i = 0; i < 8; ++i)
            v[i] = (_Float16)Wb[(size_t)(kb + i) * HID + n];
        WT[g] = v;
        return;
    }

    // ---- phase1 ----
    float* hs2 = (float*)smem;
    float4* tp = (float4*)(smem + OFF_TP);

    const int b = bid & 7;
    const int c = bid >> 3;
    const int t0 = c * CHUNK;

    if (tid < CHUNK) hs2[tid + 1] = dec[b * TT + t0 + tid];
    if (tid == 0) hs2[0] = (c == 0) ? y0[b] : dec[b * TT + t0 - 1];

    float fga[NQ], fgb[NQ];
#pragma unroll
    for (int q = 0; q < NQ; ++q) {
        int n = q * 512 + tid;
        if (n < N_MESH) {
            fgb[q] = rintf(mesh[2 * n]     * 100.0f);
            fga[q] = rintf(mesh[2 * n + 1] * 100.0f);
        } else { fga[q] = 0.f; fgb[q] = 0.f; }
    }
    __syncthreads();
    build_params(tid, hs2, tp);
    __syncthreads();

    float P[NQ], R[NQ];
    float sg0 = tp[0].w;
#pragma unroll
    for (int q = 0; q < NQ; ++q) { P[q] = 1.f; R[q] = -sg0; }

    for (int tb = 0; tb < CHUNK; tb += 8) {
#pragma unroll
        for (int j = 0; j < 8; ++j) {
            float4 p = tp[tb + j];
            bool inc = p.y > 0.f;
#pragma unroll
            for (int q = 0; q < NQ; ++q) {
                float gq = inc ? fga[q] : fgb[q];
                float A = __builtin_amdgcn_fmed3f(fmaf(p.y, gq, p.z), 0.f, 1.f);
                float r = R[q] + p.x;
                P[q] *= A;
                R[q] = r * A;
            }
        }
    }
    float sgl = tp[CHUNK - 1].w;
    size_t basew = ((size_t)(c * NB + b)) * NPAD;
#pragma unroll
    for (int q = 0; q < NQ; ++q) {
        float2 v; v.x = P[q]; v.y = R[q] + sgl;
        PQ[basew + q * 512 + tid] = v;
    }
}

// ---------------------------------------------------------------------------
// k2: blocks [0,81) = MFMA density MLP (proven body); [81,169) = phase2.
// ---------------------------------------------------------------------------
__global__ __launch_bounds__(512) void k2_mlp_phase2(
    const float* __restrict__ mesh, const float* __restrict__ Win,
    const float* __restrict__ bin,  const half8* __restrict__ WT,
    const float* __restrict__ bblk, const float* __restrict__ Wout,
    const float* __restrict__ bout, float* __restrict__ density,
    const float* __restrict__ s0_in, float* __restrict__ PQf)
{
    __shared__ __align__(16) char hA[64 * 512];   // 32 KB
    __shared__ float psum[4][16][2];
    const int tid  = threadIdx.x;

    if (blockIdx.x >= MLP_NBLK) {
        // ---- phase2: boundary states into PQ .x slot ----
        int idx = blockIdx.x - MLP_NBLK;   // 0..87
        int nbb = idx % NQ;
        int b   = idx / NQ;
        int n   = nbb * 512 + tid;
        const float2* PQ = (const float2*)PQf;
        float s = (n < N_MESH) ? s0_in[b * N_MESH + n] : 0.f;
#pragma unroll 4
        for (int c = 0; c < NCHUNK; ++c) {
            size_t ix = ((size_t)(c * NB + b)) * NPAD + n;
            float2 pv = PQ[ix];
            PQf[2 * ix] = s;
            s = fmaf(pv.x, s, pv.y);
        }
        return;
    }

    const int w    = tid >> 6;
    const int lane = tid & 63;
    const int rl   = lane & 15;
    const int cg   = lane >> 4;
    const int mt   = w & 3;
    const int nh   = w >> 2;
    const int row0 = blockIdx.x * 64;

    float hreg[8][4];

    {
        float m0[4], m1[4];
#pragma unroll
        for (int r = 0; r < 4; ++r) {
            int gr = row0 + mt * 16 + cg * 4 + r;
            if (gr < N_MESH) { m0[r] = mesh[2 * gr]; m1[r] = mesh[2 * gr + 1]; }
            else { m0[r] = 0.f; m1[r] = 0.f; }
        }
#pragma unroll
        for (int j = 0; j < 8; ++j) {
            int col = nh * 128 + j * 16 + rl;
            float wa = Win[col], wb = Win[HID + col], bi = bin[col];
#pragma unroll
            for (int r = 0; r < 4; ++r) {
                float v = fmaxf(fmaf(m0[r], wa, fmaf(m1[r], wb, bi)), 0.f);
                hreg[j][r] = v;
                *(_Float16*)(hA + swz(mt * 16 + cg * 4 + r, col * 2)) =
                    (_Float16)v;
            }
        }
    }
    __syncthreads();

    for (int L = 0; L < NLAYERS; ++L) {
        half8 af[8];
#pragma unroll
        for (int kg = 0; kg < 8; ++kg)
            af[kg] = *(const half8*)(hA + swz(mt * 16 + rl, kg * 64 + cg * 16));
        __syncthreads();

        float bias[8];
#pragma unroll
        for (int j = 0; j < 8; ++j)
            bias[j] = bblk[L * HID + nh * 128 + j * 16 + rl];

        f32x4 acc[8];
#pragma unroll
        for (int j = 0; j < 8; ++j) acc[j] = (f32x4){0.f, 0.f, 0.f, 0.f};

        const half8* WTL = WT + ((size_t)(L * 8) * 16 + nh * 8) * 64 + lane;
        half8 b0[8], b1[8];
#pragma unroll
        for (int j = 0; j < 8; ++j) b0[j] = WTL[(size_t)j * 64];
#pragma unroll
        for (int kg2 = 0; kg2 < 8; kg2 += 2) {
#pragma unroll
            for (int j = 0; j < 8; ++j)
                b1[j] = WTL[(size_t)(kg2 + 1) * 1024 + (size_t)j * 64];
#pragma unroll
            for (int j = 0; j < 8; ++j)
                acc[j] = __builtin_amdgcn_mfma_f32_16x16x32_f16(
                    af[kg2], b0[j], acc[j], 0, 0, 0);
            if (kg2 + 2 < 8) {
#pragma unroll
                for (int j = 0; j < 8; ++j)
                    b0[j] = WTL[(size_t)(kg2 + 2) * 1024 + (size_t)j * 64];
            }
#pragma unroll
            for (int j = 0; j < 8; ++j)
                acc[j] = __builtin_amdgcn_mfma_f32_16x16x32_f16(
                    af[kg2 + 1], b1[j], acc[j], 0, 0, 0);
        }

#pragma unroll
        for (int j = 0; j < 8; ++j) {
            int col = nh * 128 + j * 16 + rl;
#pragma unroll
            for (int r = 0; r < 4; ++r) {
                float v = hreg[j][r] + fmaxf(acc[j][r] + bias[j], 0.f);
                hreg[j][r] = v;
                if (L < NLAYERS - 1)
                    *(_Float16*)(hA + swz(mt * 16 + cg * 4 + r, col * 2)) =
                        (_Float16)v;
            }
        }
        if (L < NLAYERS - 1) __syncthreads();
    }

    {
        float p[4] = {0.f, 0.f, 0.f, 0.f};
#pragma unroll
        for (int j = 0; j < 8; ++j) {
            float wo = Wout[nh * 128 + j * 16 + rl];
#pragma unroll
            for (int r = 0; r < 4; ++r) p[r] = fmaf(hreg[j][r], wo, p[r]);
        }
#pragma unroll
        for (int st = 1; st < 16; st <<= 1)
#pragma unroll
            for (int r = 0; r < 4; ++r) p[r] += __shfl_xor(p[r], st, 64);
        if (rl == 0) {
#pragma unroll
            for (int r = 0; r < 4; ++r) psum[mt][cg * 4 + r][nh] = p[r];
        }
    }
    __syncthreads();
    if (tid < 64) {
        int gr = row0 + tid;
        float pp = psum[tid >> 4][tid & 15][0] + psum[tid >> 4][tid & 15][1];
        if (gr < N_MESH) density[gr] = sigmoid_fast(pp + bout[0]);
    }
}

// ---------------------------------------------------------------------------
// k3: blocks [0,512) phase3 + in-block finalize (m, b_norm);
//     blocks [512,533) density_b copy.
// ---------------------------------------------------------------------------
__global__ __launch_bounds__(512, 4) void k3_phase3_fin(
    const float* __restrict__ dec, const float* __restrict__ y0,
    const float* __restrict__ mesh, const float* __restrict__ density,
    const float* __restrict__ PQf, float* __restrict__ out)
{
    __shared__ __align__(16) char smem[SMEM3];
    const int tid = threadIdx.x;
    const int bid = blockIdx.x;

    if (bid >= SCAN_GRID) {
        // ---- density_b copy ----
        int idx = bid - SCAN_GRID;
#pragma unroll
        for (int k = 0; k < 4; ++k) {
            int j = idx * 2048 + k * 512 + tid;
            if (j < NB * N_MESH) out[OUT_DENSB + j] = density[j % N_MESH];
        }
        return;
    }

    float* hs2 = (float*)smem;
    float4* tp = (float4*)(smem + OFF_TP);
    float* red  = (float*)(smem + OFF_RED);    // [32 t][36]
    float* Dred = (float*)(smem + OFF_DRED);   // [32]

    const int b = bid & 7;
    const int c = bid >> 3;
    const int t0 = c * CHUNK;

    if (tid < CHUNK) hs2[tid + 1] = dec[b * TT + t0 + tid];
    if (tid == 0) hs2[0] = (c == 0) ? y0[b] : dec[b * TT + t0 - 1];

    float fga[NQ], fgb[NQ];
    float d[NQ], S[NQ];
#pragma unroll
    for (int q = 0; q < NQ; ++q) {
        int n = q * 512 + tid;
        if (n < N_MESH) {
            fgb[q] = rintf(mesh[2 * n]     * 100.0f);
            fga[q] = rintf(mesh[2 * n + 1] * 100.0f);
            d[q]  = density[n];
            S[q]  = PQf[2 * (((size_t)(c * NB + b)) * NPAD + n)];
        } else { fga[q] = 0.f; fgb[q] = 0.f; d[q] = 0.f; S[q] = 0.f; }
    }
    // block-local D = sum(density) (identical order in every block)
    {
        float Dp = 0.f;
#pragma unroll
        for (int q = 0; q < NQ; ++q) Dp += d[q];
        Dp = dpp16_sum(Dp);
        if ((tid & 15) == 0) Dred[tid >> 4] = Dp;
    }
    __syncthreads();
    build_params(tid, hs2, tp);
    __syncthreads();

    float z[NQ];
    float sg0 = tp[0].w;
#pragma unroll
    for (int q = 0; q < NQ; ++q) z[q] = S[q] - sg0;

    for (int tb = 0; tb < CHUNK; tb += 8) {
        float v[8];
#pragma unroll
        for (int j = 0; j < 8; ++j) {
            float4 p = tp[tb + j];
            bool inc = p.y > 0.f;
            float a0 = 0.f, a1 = 0.f;
#pragma unroll
            for (int q = 0; q < NQ; ++q) {
                float gq = inc ? fga[q] : fgb[q];
                float A = __builtin_amdgcn_fmed3f(fmaf(p.y, gq, p.z), 0.f, 1.f);
                float zn = (z[q] + p.x) * A;
                z[q] = zn;
                if (q & 1) a1 = fmaf(d[q], zn, a1);
                else       a0 = fmaf(d[q], zn, a0);
            }
            v[j] = a0 + a1;
        }
#pragma unroll
        for (int j = 0; j < 8; ++j) v[j] = dpp16_sum(v[j]);
        float outv = v[0];
#pragma unroll
        for (int j = 1; j < 8; ++j) if ((tid & 15) == j) outv = v[j];
        if ((tid & 15) < 8)
            red[(tb + (tid & 15)) * 36 + (tid >> 4)] = outv;
    }
    __syncthreads();

    // finalize: 32 threads, one per t in this chunk
    if (tid < CHUNK) {
        float acc = 0.f;
#pragma unroll
        for (int g4 = 0; g4 < 32; g4 += 4) {
            float4 r4 = *(const float4*)&red[tid * 36 + g4];
            acc += (r4.x + r4.y) + (r4.z + r4.w);
        }
        float D = 0.f;
#pragma unroll
        for (int g4 = 0; g4 < 32; g4 += 4) {
            float4 d4 = *(const float4*)&Dred[g4];
            D += (d4.x + d4.y) + (d4.z + d4.w);
        }
        float gd = tp[tid].w;                // direction sign at t
        int t = t0 + tid;
        float m = (acc + gd * D) / D;
        out[OUT_M + b * TT + t] = m;
        out[OUT_BNORM + b * TT + t] = 0.5f * m + 0.5f;
    }
}

extern "C" void kernel_launch(void* const* d_in, const int* in_sizes, int n_in,
                              void* d_out, int out_size, void* d_ws, size_t ws_size,
                              hipStream_t stream) {
    const float* dec  = (const float*)d_in[1];
    const float* s0   = (const float*)d_in[2];
    const float* y0   = (const float*)d_in[3];
    const float* mesh = (const float*)d_in[4];
    const float* Win  = (const float*)d_in[5];
    const float* bin  = (const float*)d_in[6];
    const float* Wblk = (const float*)d_in[7];
    const float* bblk = (const float*)d_in[8];
    const float* Wout = (const float*)d_in[9];
    const float* bout = (const float*)d_in[10];
    float* out = (float*)d_out;
    float* ws  = (float*)d_ws;

    float*  density  = ws + WS_DENSITY;
    half8*  wt       = (half8*)(ws + WS_WT);
    float*  pqf      = ws + WS_PQ;
    float2* pq       = (float2*)pqf;

    k1_scan1_prep<<<SCAN_GRID + PREP_NBLK + COPY_NBLK, 512, 0, stream>>>(
        dec, y0, mesh, Wblk, pq, wt, s0, out);
    k2_mlp_phase2<<<MLP_NBLK + PH2_NBLK, 512, 0, stream>>>(
        mesh, Win, bin, wt, bblk, Wout, bout, density, s0, pqf);
    k3_phase3_fin<<<SCAN_GRID + DENSB_NBLK, 512, 0, stream>>>(
        dec, y0, mesh, density, pqf, out);
}

// Round 19
// 61.065 us; speedup vs baseline: 2.6551x; 1.0983x over previous
//
#include <hip/hip_runtime.h>
#include <hip/hip_fp16.h>
#include <math.h>

#define N_MESH   5151
#define NB       8
#define TT       2048
#define HID      256
#define NLAYERS  3
#define NCHUNK   64
#define CHUNK    32            // TT / NCHUNK
#define NQ       11            // mesh points per thread (11*512 = 5632)
#define NPAD     5632
#define SCAN_GRID 512          // 8 b x 64 c, one block per (b,c)
#define PREP_NBLK 48           // 24576 / 512
#define COPY_NBLK 61           // 123624 / 2048 rounded up
#define MLP_NBLK  81           // 81*64 rows
#define PH2_NBLK  88           // 11 x 8
#define DENSB_NBLK 21          // 41208 / 2048 rounded up

// scan smem layout (bytes): hs2[34] @0 (pad to 144), tp[32] float4 @144
#define OFF_TP    144
#define SMEM1     656
#define OFF_RED   656          // k3: [32 t][36] floats = 4608
#define OFF_DRED  5264         // k3: [32] floats
#define SMEM3     5392

// ws layout (floats)
#define WS_DENSITY 0           // 5151
#define WS_WT      6144        // 98304 floats (24576 half8)
#define WS_PQ      104448      // NCHUNK*NB*NPAD*2 = 5767168 -> ends 5871616
#define WS_S       5871616     // NCHUNK*NB*NPAD = 2883584 -> ends 8755200 (~35MB)

// out layout (floats)
#define OUT_BNORM  0           // 16384
#define OUT_DENSB  16384       // 41208
#define OUT_M      57592       // 16384
#define OUT_S0     73976       // 41208
#define OUT_MESHB  115184      // 82416

typedef _Float16 half8  __attribute__((ext_vector_type(8)));
typedef float    f32x4  __attribute__((ext_vector_type(4)));

__device__ __forceinline__ float sigmoid_fast(float x) {
    float e = __expf(-x);
    return __builtin_amdgcn_rcpf(1.0f + e);
}

// hA byte offset with XOR swizzle (row stride 512 B fp16) -- MLP only
__device__ __forceinline__ int swz(int row, int kbyte) {
    return row * 512 + (kbyte ^ ((row & 7) << 4));
}

// 16-lane sum via DPP (VALU pipe, zero DS ops)
__device__ __forceinline__ float dpp16_sum(float v) {
    int a;
    a = __builtin_amdgcn_update_dpp(0, __float_as_int(v), 0xB1, 0xF, 0xF, true);
    v += __int_as_float(a);
    a = __builtin_amdgcn_update_dpp(0, __float_as_int(v), 0x4E, 0xF, 0xF, true);
    v += __int_as_float(a);
    a = __builtin_amdgcn_update_dpp(0, __float_as_int(v), 0x141, 0xF, 0xF, true);
    v += __int_as_float(a);
    a = __builtin_amdgcn_update_dpp(0, __float_as_int(v), 0x140, 0xF, 0xF, true);
    v += __int_as_float(a);
    return v;
}

// Per-t wave-uniform params: {dl, u, v, sg}.
// inc: A = med3(g + v, 0, 1); dec: A = med3(v - g, 0, 1)
__device__ __forceinline__ void build_params(int tid, const float* hs2,
                                             float4* tp)
{
    if (tid < CHUNK) {
        float ht = hs2[tid + 1];
        float hp = hs2[tid];
        bool inc = (ht >= hp);
        float sg = inc ? 1.f : -1.f;
        float psg = sg;
        if (tid > 0) psg = (hs2[tid] >= hs2[tid - 1]) ? 1.f : -1.f;
        float x = ht * 1000.f;
        float gc = rintf(ht * 100.f);
        float4 p;
        p.x = psg - sg;                       // dl (0 or +-2)
        if (inc) {
            float Ac = sigmoid_fast(fmaf(10.f, gc, -x));
            p.y = 1.f;  p.z = Ac - gc;
        } else {
            float Ac = sigmoid_fast(fmaf(-10.f, gc, x));
            p.y = -1.f; p.z = gc + Ac;
        }
        p.w = sg;
        tp[tid] = p;
    }
}

// ---------------------------------------------------------------------------
// k1: blocks [0,512) phase1; [512,560) W prep; [560,621) s0/mesh_b copies.
// ---------------------------------------------------------------------------
__global__ __launch_bounds__(512, 4) void k1_scan1_prep(
    const float* __restrict__ dec, const float* __restrict__ y0,
    const float* __restrict__ mesh, const float* __restrict__ Wblk,
    float2* __restrict__ PQ, half8* __restrict__ WT,
    const float* __restrict__ s0, float* __restrict__ out)
{
    __shared__ __align__(16) char smem[SMEM1];
    const int tid = threadIdx.x;
    const int bid = blockIdx.x;

    if (bid >= SCAN_GRID + PREP_NBLK) {
        // ---- s0 / mesh_b copies ----
        int idx = bid - (SCAN_GRID + PREP_NBLK);
        const int n1 = NB * N_MESH;                 // 41208
        const int total = 3 * n1;                   // 123624
#pragma unroll
        for (int k = 0; k < 4; ++k) {
            int j = idx * 2048 + k * 512 + tid;
            if (j < total) {
                if (j < n1) out[OUT_S0 + j] = s0[j];
                else {
                    int jj = j - n1;
                    out[OUT_MESHB + jj] = mesh[jj % (2 * N_MESH)];
                }
            }
        }
        return;
    }

    if (bid >= SCAN_GRID) {
        // ---- prep: gather W into per-lane MFMA fragment order ----
        int g = (bid - SCAN_GRID) * 512 + tid;   // [0, 24576)
        int l  = g & 63;
        int nt = (g >> 6) & 15;
        int kg = (g >> 10) & 7;
        int L  = g >> 13;
        int n  = nt * 16 + (l & 15);
        int kb = kg * 32 + ((l >> 4) & 3) * 8;
        const float* Wb = Wblk + (size_t)L * HID * HID;
        half8 v;
#pragma unroll
        for (int i = 0; i < 8; ++i)
            v[i] = (_Float16)Wb[(size_t)(kb + i) * HID + n];
        WT[g] = v;
        return;
    }

    // ---- phase1 ----
    float* hs2 = (float*)smem;
    float4* tp = (float4*)(smem + OFF_TP);

    const int b = bid & 7;
    const int c = bid >> 3;
    const int t0 = c * CHUNK;

    if (tid < CHUNK) hs2[tid + 1] = dec[b * TT + t0 + tid];
    if (tid == 0) hs2[0] = (c == 0) ? y0[b] : dec[b * TT + t0 - 1];

    float fga[NQ], fgb[NQ];
#pragma unroll
    for (int q = 0; q < NQ; ++q) {
        int n = q * 512 + tid;
        if (n < N_MESH) {
            float2 mv = *(const float2*)&mesh[2 * n];
            fgb[q] = rintf(mv.x * 100.0f);
            fga[q] = rintf(mv.y * 100.0f);
        } else { fga[q] = 0.f; fgb[q] = 0.f; }
    }
    __syncthreads();
    build_params(tid, hs2, tp);
    __syncthreads();

    float P[NQ], R[NQ];
    float sg0 = tp[0].w;
#pragma unroll
    for (int q = 0; q < NQ; ++q) { P[q] = 1.f; R[q] = -sg0; }

    for (int tb = 0; tb < CHUNK; tb += 8) {
#pragma unroll
        for (int j = 0; j < 8; ++j) {
            float4 p = tp[tb + j];
            bool inc = p.y > 0.f;
            bool dl0 = p.x == 0.f;
            if (inc) {
                if (dl0) {
#pragma unroll
                    for (int q = 0; q < NQ; ++q) {
                        float A = __builtin_amdgcn_fmed3f(fga[q] + p.z, 0.f, 1.f);
                        P[q] *= A;
                        R[q] *= A;
                    }
                } else {
#pragma unroll
                    for (int q = 0; q < NQ; ++q) {
                        float A = __builtin_amdgcn_fmed3f(fga[q] + p.z, 0.f, 1.f);
                        P[q] *= A;
                        R[q] = (R[q] + p.x) * A;
                    }
                }
            } else {
                if (dl0) {
#pragma unroll
                    for (int q = 0; q < NQ; ++q) {
                        float A = __builtin_amdgcn_fmed3f(p.z - fgb[q], 0.f, 1.f);
                        P[q] *= A;
                        R[q] *= A;
                    }
                } else {
#pragma unroll
                    for (int q = 0; q < NQ; ++q) {
                        float A = __builtin_amdgcn_fmed3f(p.z - fgb[q], 0.f, 1.f);
                        P[q] *= A;
                        R[q] = (R[q] + p.x) * A;
                    }
                }
            }
        }
    }
    float sgl = tp[CHUNK - 1].w;
    size_t basew = ((size_t)(c * NB + b)) * NPAD;
#pragma unroll
    for (int q = 0; q < NQ; ++q) {
        float2 v; v.x = P[q]; v.y = R[q] + sgl;
        PQ[basew + q * 512 + tid] = v;
    }
}

// ---------------------------------------------------------------------------
// k2: blocks [0,81) = MFMA density MLP (proven body); [81,169) = phase2.
// ---------------------------------------------------------------------------
__global__ __launch_bounds__(512) void k2_mlp_phase2(
    const float* __restrict__ mesh, const float* __restrict__ Win,
    const float* __restrict__ bin,  const half8* __restrict__ WT,
    const float* __restrict__ bblk, const float* __restrict__ Wout,
    const float* __restrict__ bout, float* __restrict__ density,
    const float* __restrict__ s0_in, const float2* __restrict__ PQ,
    float* __restrict__ Sarr)
{
    __shared__ __align__(16) char hA[64 * 512];   // 32 KB
    __shared__ float psum[4][16][2];
    const int tid  = threadIdx.x;

    if (blockIdx.x >= MLP_NBLK) {
        // ---- phase2: boundary states into dense Sarr ----
        int idx = blockIdx.x - MLP_NBLK;   // 0..87
        int nbb = idx % NQ;
        int b   = idx / NQ;
        int n   = nbb * 512 + tid;
        float s = (n < N_MESH) ? s0_in[b * N_MESH + n] : 0.f;
#pragma unroll 4
        for (int c = 0; c < NCHUNK; ++c) {
            size_t ix = ((size_t)(c * NB + b)) * NPAD + n;
            float2 pv = PQ[ix];
            Sarr[ix] = s;
            s = fmaf(pv.x, s, pv.y);
        }
        return;
    }

    const int w    = tid >> 6;
    const int lane = tid & 63;
    const int rl   = lane & 15;
    const int cg   = lane >> 4;
    const int mt   = w & 3;
    const int nh   = w >> 2;
    const int row0 = blockIdx.x * 64;

    float hreg[8][4];

    {
        float m0[4], m1[4];
#pragma unroll
        for (int r = 0; r < 4; ++r) {
            int gr = row0 + mt * 16 + cg * 4 + r;
            if (gr < N_MESH) { m0[r] = mesh[2 * gr]; m1[r] = mesh[2 * gr + 1]; }
            else { m0[r] = 0.f; m1[r] = 0.f; }
        }
#pragma unroll
        for (int j = 0; j < 8; ++j) {
            int col = nh * 128 + j * 16 + rl;
            float wa = Win[col], wb = Win[HID + col], bi = bin[col];
#pragma unroll
            for (int r = 0; r < 4; ++r) {
                float v = fmaxf(fmaf(m0[r], wa, fmaf(m1[r], wb, bi)), 0.f);
                hreg[j][r] = v;
                *(_Float16*)(hA + swz(mt * 16 + cg * 4 + r, col * 2)) =
                    (_Float16)v;
            }
        }
    }
    __syncthreads();

    for (int L = 0; L < NLAYERS; ++L) {
        half8 af[8];
#pragma unroll
        for (int kg = 0; kg < 8; ++kg)
            af[kg] = *(const half8*)(hA + swz(mt * 16 + rl, kg * 64 + cg * 16));
        __syncthreads();

        float bias[8];
#pragma unroll
        for (int j = 0; j < 8; ++j)
            bias[j] = bblk[L * HID + nh * 128 + j * 16 + rl];

        f32x4 acc[8];
#pragma unroll
        for (int j = 0; j < 8; ++j) acc[j] = (f32x4){0.f, 0.f, 0.f, 0.f};

        const half8* WTL = WT + ((size_t)(L * 8) * 16 + nh * 8) * 64 + lane;
        half8 b0[8], b1[8];
#pragma unroll
        for (int j = 0; j < 8; ++j) b0[j] = WTL[(size_t)j * 64];
#pragma unroll
        for (int kg2 = 0; kg2 < 8; kg2 += 2) {
#pragma unroll
            for (int j = 0; j < 8; ++j)
                b1[j] = WTL[(size_t)(kg2 + 1) * 1024 + (size_t)j * 64];
#pragma unroll
            for (int j = 0; j < 8; ++j)
                acc[j] = __builtin_amdgcn_mfma_f32_16x16x32_f16(
                    af[kg2], b0[j], acc[j], 0, 0, 0);
            if (kg2 + 2 < 8) {
#pragma unroll
                for (int j = 0; j < 8; ++j)
                    b0[j] = WTL[(size_t)(kg2 + 2) * 1024 + (size_t)j * 64];
            }
#pragma unroll
            for (int j = 0; j < 8; ++j)
                acc[j] = __builtin_amdgcn_mfma_f32_16x16x32_f16(
                    af[kg2 + 1], b1[j], acc[j], 0, 0, 0);
        }

#pragma unroll
        for (int j = 0; j < 8; ++j) {
            int col = nh * 128 + j * 16 + rl;
#pragma unroll
            for (int r = 0; r < 4; ++r) {
                float v = hreg[j][r] + fmaxf(acc[j][r] + bias[j], 0.f);
                hreg[j][r] = v;
                if (L < NLAYERS - 1)
                    *(_Float16*)(hA + swz(mt * 16 + cg * 4 + r, col * 2)) =
                        (_Float16)v;
            }
        }
        if (L < NLAYERS - 1) __syncthreads();
    }

    {
        float p[4] = {0.f, 0.f, 0.f, 0.f};
#pragma unroll
        for (int j = 0; j < 8; ++j) {
            float wo = Wout[nh * 128 + j * 16 + rl];
#pragma unroll
            for (int r = 0; r < 4; ++r) p[r] = fmaf(hreg[j][r], wo, p[r]);
        }
#pragma unroll
        for (int st = 1; st < 16; st <<= 1)
#pragma unroll
            for (int r = 0; r < 4; ++r) p[r] += __shfl_xor(p[r], st, 64);
        if (rl == 0) {
#pragma unroll
            for (int r = 0; r < 4; ++r) psum[mt][cg * 4 + r][nh] = p[r];
        }
    }
    __syncthreads();
    if (tid < 64) {
        int gr = row0 + tid;
        float pp = psum[tid >> 4][tid & 15][0] + psum[tid >> 4][tid & 15][1];
        if (gr < N_MESH) density[gr] = sigmoid_fast(pp + bout[0]);
    }
}

// ---------------------------------------------------------------------------
// k3: blocks [0,512) phase3 + in-block finalize; [512,533) density_b copy.
// ---------------------------------------------------------------------------
__global__ __launch_bounds__(512, 4) void k3_phase3_fin(
    const float* __restrict__ dec, const float* __restrict__ y0,
    const float* __restrict__ mesh, const float* __restrict__ density,
    const float* __restrict__ Sarr, float* __restrict__ out)
{
    __shared__ __align__(16) char smem[SMEM3];
    const int tid = threadIdx.x;
    const int bid = blockIdx.x;

    if (bid >= SCAN_GRID) {
        // ---- density_b copy ----
        int idx = bid - SCAN_GRID;
#pragma unroll
        for (int k = 0; k < 4; ++k) {
            int j = idx * 2048 + k * 512 + tid;
            if (j < NB * N_MESH) out[OUT_DENSB + j] = density[j % N_MESH];
        }
        return;
    }

    float* hs2 = (float*)smem;
    float4* tp = (float4*)(smem + OFF_TP);
    float* red  = (float*)(smem + OFF_RED);    // [32 t][36]
    float* Dred = (float*)(smem + OFF_DRED);   // [32]

    const int b = bid & 7;
    const int c = bid >> 3;
    const int t0 = c * CHUNK;

    if (tid < CHUNK) hs2[tid + 1] = dec[b * TT + t0 + tid];
    if (tid == 0) hs2[0] = (c == 0) ? y0[b] : dec[b * TT + t0 - 1];

    float fga[NQ], fgb[NQ];
    float d[NQ], S[NQ];
#pragma unroll
    for (int q = 0; q < NQ; ++q) {
        int n = q * 512 + tid;
        if (n < N_MESH) {
            float2 mv = *(const float2*)&mesh[2 * n];
            fgb[q] = rintf(mv.x * 100.0f);
            fga[q] = rintf(mv.y * 100.0f);
            d[q]  = density[n];
            S[q]  = Sarr[((size_t)(c * NB + b)) * NPAD + n];
        } else { fga[q] = 0.f; fgb[q] = 0.f; d[q] = 0.f; S[q] = 0.f; }
    }
    // block-local D = sum(density) (identical order in every block)
    {
        float Dp = 0.f;
#pragma unroll
        for (int q = 0; q < NQ; ++q) Dp += d[q];
        Dp = dpp16_sum(Dp);
        if ((tid & 15) == 0) Dred[tid >> 4] = Dp;
    }
    __syncthreads();
    build_params(tid, hs2, tp);
    __syncthreads();

    float z[NQ];
    float sg0 = tp[0].w;
#pragma unroll
    for (int q = 0; q < NQ; ++q) z[q] = S[q] - sg0;

    for (int tb = 0; tb < CHUNK; tb += 8) {
        float v[8];
#pragma unroll
        for (int j = 0; j < 8; ++j) {
            float4 p = tp[tb + j];
            bool inc = p.y > 0.f;
            bool dl0 = p.x == 0.f;
            float a0 = 0.f, a1 = 0.f;
            if (inc) {
                if (dl0) {
#pragma unroll
                    for (int q = 0; q < NQ; ++q) {
                        float A = __builtin_amdgcn_fmed3f(fga[q] + p.z, 0.f, 1.f);
                        float zn = z[q] * A;
                        z[q] = zn;
                        if (q & 1) a1 = fmaf(d[q], zn, a1);
                        else       a0 = fmaf(d[q], zn, a0);
                    }
                } else {
#pragma unroll
                    for (int q = 0; q < NQ; ++q) {
                        float A = __builtin_amdgcn_fmed3f(fga[q] + p.z, 0.f, 1.f);
                        float zn = (z[q] + p.x) * A;
                        z[q] = zn;
                        if (q & 1) a1 = fmaf(d[q], zn, a1);
                        else       a0 = fmaf(d[q], zn, a0);
                    }
                }
            } else {
                if (dl0) {
#pragma unroll
                    for (int q = 0; q < NQ; ++q) {
                        float A = __builtin_amdgcn_fmed3f(p.z - fgb[q], 0.f, 1.f);
                        float zn = z[q] * A;
                        z[q] = zn;
                        if (q & 1) a1 = fmaf(d[q], zn, a1);
                        else       a0 = fmaf(d[q], zn, a0);
                    }
                } else {
#pragma unroll
                    for (int q = 0; q < NQ; ++q) {
                        float A = __builtin_amdgcn_fmed3f(p.z - fgb[q], 0.f, 1.f);
                        float zn = (z[q] + p.x) * A;
                        z[q] = zn;
                        if (q & 1) a1 = fmaf(d[q], zn, a1);
                        else       a0 = fmaf(d[q], zn, a0);
                    }
                }
            }
            v[j] = a0 + a1;
        }
#pragma unroll
        for (int j = 0; j < 8; ++j) v[j] = dpp16_sum(v[j]);
        float outv = v[0];
#pragma unroll
        for (int j = 1; j < 8; ++j) if ((tid & 15) == j) outv = v[j];
        if ((tid & 15) < 8)
            red[(tb + (tid & 15)) * 36 + (tid >> 4)] = outv;
    }
    __syncthreads();

    // finalize: 32 threads, one per t in this chunk
    if (tid < CHUNK) {
        float acc = 0.f;
#pragma unroll
        for (int g4 = 0; g4 < 32; g4 += 4) {
            float4 r4 = *(const float4*)&red[tid * 36 + g4];
            acc += (r4.x + r4.y) + (r4.z + r4.w);
        }
        float D = 0.f;
#pragma unroll
        for (int g4 = 0; g4 < 32; g4 += 4) {
            float4 d4 = *(const float4*)&Dred[g4];
            D += (d4.x + d4.y) + (d4.z + d4.w);
        }
        float gd = tp[tid].w;                // direction sign at t
        int t = t0 + tid;
        float m = (acc + gd * D) / D;
        out[OUT_M + b * TT + t] = m;
        out[OUT_BNORM + b * TT + t] = 0.5f * m + 0.5f;
    }
}

extern "C" void kernel_launch(void* const* d_in, const int* in_sizes, int n_in,
                              void* d_out, int out_size, void* d_ws, size_t ws_size,
                              hipStream_t stream) {
    const float* dec  = (const float*)d_in[1];
    const float* s0   = (const float*)d_in[2];
    const float* y0   = (const float*)d_in[3];
    const float* mesh = (const float*)d_in[4];
    const float* Win  = (const float*)d_in[5];
    const float* bin  = (const float*)d_in[6];
    const float* Wblk = (const float*)d_in[7];
    const float* bblk = (const float*)d_in[8];
    const float* Wout = (const float*)d_in[9];
    const float* bout = (const float*)d_in[10];
    float* out = (float*)d_out;
    float* ws  = (float*)d_ws;

    float*  density  = ws + WS_DENSITY;
    half8*  wt       = (half8*)(ws + WS_WT);
    float*  pqf      = ws + WS_PQ;
    float2* pq       = (float2*)pqf;
    float*  sarr     = ws + WS_S;

    k1_scan1_prep<<<SCAN_GRID + PREP_NBLK + COPY_NBLK, 512, 0, stream>>>(
        dec, y0, mesh, Wblk, pq, wt, s0, out);
    k2_mlp_phase2<<<MLP_NBLK + PH2_NBLK, 512, 0, stream>>>(
        mesh, Win, bin, wt, bblk, Wout, bout, density, s0, pq, sarr);
    k3_phase3_fin<<<SCAN_GRID + DENSB_NBLK, 512, 0, stream>>>(
        dec, y0, mesh, density, sarr, out);
}